// Round 1
// baseline (393.963 us; speedup 1.0000x reference)
//
#include <hip/hip_runtime.h>

#define NB 64         // batches
#define NN 256        // nodes per graph
#define IND 7
#define HIDD 64
#define OUTD 32
#define EPG 8192      // edges per graph
#define ETOT 524288   // edges per side total
#define CAP 5500      // CSR capacity per half-graph (mean 4224, ~28 sigma margin)

typedef _Float16 f16;
typedef f16 f16x2 __attribute__((ext_vector_type(2)));

// ---------------- block reductions (rbuf: >=4 floats) ----------------
__device__ __forceinline__ float blk_sum(float v, float* rb){
#pragma unroll
  for (int off = 32; off > 0; off >>= 1) v += __shfl_xor(v, off, 64);
  int lane = threadIdx.x & 63, wid = threadIdx.x >> 6;
  __syncthreads();
  if (lane == 0) rb[wid] = v;
  __syncthreads();
  return rb[0] + rb[1] + rb[2] + rb[3];
}
__device__ __forceinline__ float blk_min(float v, float* rb){
#pragma unroll
  for (int off = 32; off > 0; off >>= 1) v = fminf(v, __shfl_xor(v, off, 64));
  int lane = threadIdx.x & 63, wid = threadIdx.x >> 6;
  __syncthreads();
  if (lane == 0) rb[wid] = v;
  __syncthreads();
  return fminf(fminf(rb[0], rb[1]), fminf(rb[2], rb[3]));
}
__device__ __forceinline__ float blk_max(float v, float* rb){
#pragma unroll
  for (int off = 32; off > 0; off >>= 1) v = fmaxf(v, __shfl_xor(v, off, 64));
  int lane = threadIdx.x & 63, wid = threadIdx.x >> 6;
  __syncthreads();
  if (lane == 0) rb[wid] = v;
  __syncthreads();
  return fmaxf(fmaxf(rb[0], rb[1]), fmaxf(rb[2], rb[3]));
}

// ---------------- GAT layer 1: x[NT,7] -> relu(gatv2) -> hmid f16 [128][256][64]
// grid 256: block = (graph-side gs = bid>>1, dst-half = bid&1), 256 threads.
__global__ __launch_bounds__(256) void gat1(
    const float* __restrict__ x1, const float* __restrict__ x2,
    const int* __restrict__ e1, const int* __restrict__ e2,
    const float* __restrict__ Wl, const float* __restrict__ Wr,
    const float* __restrict__ bl, const float* __restrict__ br,
    const float* __restrict__ att, const float* __restrict__ bias,
    f16x2* __restrict__ hmid)
{
  __shared__ f16x2 xl_s[256 * 33];          // 64 dims padded to 33 f16x2 rows
  __shared__ float sc_s[CAP];
  __shared__ unsigned char src_s[CAP];
  __shared__ int deg_s[128], start_s[128], cnt_s[128];
  __shared__ int wavesum[4];

  const int bid = blockIdx.x;
  const int gs = bid >> 1, half = bid & 1;
  const int side = gs >> 6, g = gs & 63;
  const float* x = side ? x2 : x1;
  const int* eb = side ? e2 : e1;
  const int* es = eb + g * EPG;
  const int* ed = eb + ETOT + g * EPG;
  const int lo = half * 128;
  const int t = threadIdx.x;

  // ---- xl = x@Wl + bl for node t (all 256 srcs), stored f16 in LDS
  {
    float xv[IND];
    const float* xr_ = x + (g * 256 + t) * IND;
#pragma unroll
    for (int k = 0; k < IND; k++) xv[k] = xr_[k];
#pragma unroll
    for (int d = 0; d < HIDD; d += 2){
      float a0 = bl[d], a1 = bl[d + 1];
#pragma unroll
      for (int k = 0; k < IND; k++){
        a0 = fmaf(xv[k], Wl[k * HIDD + d], a0);
        a1 = fmaf(xv[k], Wl[k * HIDD + d + 1], a1);
      }
      f16x2 p; p.x = (f16)a0; p.y = (f16)a1;
      xl_s[t * 33 + (d >> 1)] = p;
    }
  }

  // ---- 2 threads per dst: xr (f32 regs) + att chunk
  const int pairi = t >> 1, sub = t & 1, ln = lo + pairi;
  float xrv[32], attv[32];
  {
    float xv[IND];
    const float* xq = x + (g * 256 + ln) * IND;
#pragma unroll
    for (int k = 0; k < IND; k++) xv[k] = xq[k];
#pragma unroll
    for (int d = 0; d < 32; d++){
      float a = br[sub * 32 + d];
#pragma unroll
      for (int k = 0; k < IND; k++) a = fmaf(xv[k], Wr[k * HIDD + sub * 32 + d], a);
      xrv[d] = a;
      attv[d] = att[sub * 32 + d];
    }
  }

  // ---- CSR build over this half's dsts (8192 edges + 256 self loops)
  if (t < 128) deg_s[t] = 0;
  __syncthreads();
  for (int e = t; e < EPG + 256; e += 256){
    int dl = (e < EPG) ? (ed[e] & 255) : (e - EPG);
    int r = dl - lo;
    if ((unsigned)r < 128u) atomicAdd(&deg_s[r], 1);
  }
  __syncthreads();
  {
    int v = (t < 128) ? deg_s[t] : 0;
    int lane = t & 63, wid = t >> 6;
    int s = v;
#pragma unroll
    for (int off = 1; off < 64; off <<= 1){
      int u = __shfl_up(s, off, 64);
      if (lane >= off) s += u;
    }
    if (lane == 63) wavesum[wid] = s;
    __syncthreads();
    if (t < 128){
      int o = (wid == 1) ? wavesum[0] : 0;
      start_s[t] = s - v + o;
      cnt_s[t] = s - v + o;
    }
  }
  __syncthreads();
  for (int e = t; e < EPG + 256; e += 256){
    int sl, dl;
    if (e < EPG){ sl = es[e] & 255; dl = ed[e] & 255; }
    else { sl = dl = e - EPG; }
    int r = dl - lo;
    if ((unsigned)r < 128u){
      int p = atomicAdd(&cnt_s[r], 1);
      if (p < CAP) src_s[p] = (unsigned char)sl;
    }
  }
  __syncthreads();

  // ---- scores: score = att . leaky_relu(xl[src] + xr[dst])
  const int s0 = start_s[pairi];
  int sE = s0 + deg_s[pairi];
  if (sE > CAP) sE = CAP;
  float smax = -3.0e38f;
  for (int idx = s0; idx < sE; idx++){
    int sl = src_s[idx];
    float sc = 0.f;
    int base = sl * 33 + sub * 16;
#pragma unroll
    for (int c = 0; c < 16; c++){
      f16x2 a = xl_s[base + c];
      float t0 = (float)a.x + xrv[2 * c];
      float t1 = (float)a.y + xrv[2 * c + 1];
      float l0 = fmaxf(t0, 0.2f * t0);
      float l1 = fmaxf(t1, 0.2f * t1);
      sc = fmaf(l0, attv[2 * c], sc);
      sc = fmaf(l1, attv[2 * c + 1], sc);
    }
    sc += __shfl_xor(sc, 1, 64);          // combine the two dim-halves
    if (sub == 0) sc_s[idx] = sc;
    smax = fmaxf(smax, sc);
  }
  // ---- softmax weights (in-wave: read-before-overwrite is lockstep-safe)
  float ssum = 0.f;
  for (int idx = s0; idx < sE; idx++){
    float w = __expf(sc_s[idx] - smax);
    ssum += w;
    if (sub == 0) sc_s[idx] = w;
  }
  float inv = 1.f / ssum;
  // ---- aggregate alpha * xl[src]
  float acc[32];
#pragma unroll
  for (int c = 0; c < 32; c++) acc[c] = 0.f;
  for (int idx = s0; idx < sE; idx++){
    int sl = src_s[idx];
    float w = sc_s[idx];
    int base = sl * 33 + sub * 16;
#pragma unroll
    for (int c = 0; c < 16; c++){
      f16x2 a = xl_s[base + c];
      acc[2 * c] = fmaf(w, (float)a.x, acc[2 * c]);
      acc[2 * c + 1] = fmaf(w, (float)a.y, acc[2 * c + 1]);
    }
  }
  f16x2* orow = hmid + (size_t)(gs * 256 + ln) * 32 + sub * 16;
#pragma unroll
  for (int c = 0; c < 16; c++){
    float v0 = fmaxf(fmaf(acc[2 * c], inv, 0.f) + bias[sub * 32 + 2 * c], 0.f);
    float v1 = fmaxf(fmaf(acc[2 * c + 1], inv, 0.f) + bias[sub * 32 + 2 * c + 1], 0.f);
    f16x2 p; p.x = (f16)v0; p.y = (f16)v1;
    orow[c] = p;
  }
}

// ---------------- GAT layer 2: hmid[.,64] -> gatv2 -> hfin f16 [128][256][32] (no relu)
__global__ __launch_bounds__(256) void gat2(
    const int* __restrict__ e1, const int* __restrict__ e2,
    const f16x2* __restrict__ hmid,
    const float* __restrict__ Wl, const float* __restrict__ Wr,
    const float* __restrict__ bl, const float* __restrict__ br,
    const float* __restrict__ att, const float* __restrict__ bias,
    f16x2* __restrict__ hout)
{
  __shared__ f16x2 xl_s[256 * 17];          // 32 dims padded to 17 f16x2 rows
  __shared__ float sc_s[CAP];
  __shared__ unsigned char src_s[CAP];
  __shared__ int deg_s[128], start_s[128], cnt_s[128];
  __shared__ int wavesum[4];

  const int bid = blockIdx.x;
  const int gs = bid >> 1, half = bid & 1;
  const int side = gs >> 6, g = gs & 63;
  const int* eb = side ? e2 : e1;
  const int* es = eb + g * EPG;
  const int* ed = eb + ETOT + g * EPG;
  const int lo = half * 128;
  const int t = threadIdx.x;

  // ---- xl2 = h@Wl2 + bl2 for node t
  {
    const f16x2* hr = hmid + (size_t)(gs * 256 + t) * 32;
    float acc[32];
#pragma unroll
    for (int d = 0; d < 32; d++) acc[d] = bl[d];
    for (int k = 0; k < 64; k += 2){
      f16x2 hp = hr[k >> 1];
      float h0 = (float)hp.x, h1 = (float)hp.y;
#pragma unroll
      for (int d = 0; d < 32; d++){
        acc[d] = fmaf(h0, Wl[k * 32 + d], acc[d]);
        acc[d] = fmaf(h1, Wl[(k + 1) * 32 + d], acc[d]);
      }
    }
#pragma unroll
    for (int d = 0; d < 32; d += 2){
      f16x2 p; p.x = (f16)acc[d]; p.y = (f16)acc[d + 1];
      xl_s[t * 17 + (d >> 1)] = p;
    }
  }

  // ---- 2 threads/dst: xr2 chunk (16 dims each)
  const int pairi = t >> 1, sub = t & 1, ln = lo + pairi;
  float xrv[16], attv[16];
  {
    const f16x2* hr = hmid + (size_t)(gs * 256 + ln) * 32;
    float acc[16];
#pragma unroll
    for (int d = 0; d < 16; d++) acc[d] = br[sub * 16 + d];
    for (int k = 0; k < 64; k += 2){
      f16x2 hp = hr[k >> 1];
      float h0 = (float)hp.x, h1 = (float)hp.y;
#pragma unroll
      for (int d = 0; d < 16; d++){
        acc[d] = fmaf(h0, Wr[k * 32 + sub * 16 + d], acc[d]);
        acc[d] = fmaf(h1, Wr[(k + 1) * 32 + sub * 16 + d], acc[d]);
      }
    }
#pragma unroll
    for (int d = 0; d < 16; d++){ xrv[d] = acc[d]; attv[d] = att[sub * 16 + d]; }
  }

  // ---- CSR build (same edges as layer 1)
  if (t < 128) deg_s[t] = 0;
  __syncthreads();
  for (int e = t; e < EPG + 256; e += 256){
    int dl = (e < EPG) ? (ed[e] & 255) : (e - EPG);
    int r = dl - lo;
    if ((unsigned)r < 128u) atomicAdd(&deg_s[r], 1);
  }
  __syncthreads();
  {
    int v = (t < 128) ? deg_s[t] : 0;
    int lane = t & 63, wid = t >> 6;
    int s = v;
#pragma unroll
    for (int off = 1; off < 64; off <<= 1){
      int u = __shfl_up(s, off, 64);
      if (lane >= off) s += u;
    }
    if (lane == 63) wavesum[wid] = s;
    __syncthreads();
    if (t < 128){
      int o = (wid == 1) ? wavesum[0] : 0;
      start_s[t] = s - v + o;
      cnt_s[t] = s - v + o;
    }
  }
  __syncthreads();
  for (int e = t; e < EPG + 256; e += 256){
    int sl, dl;
    if (e < EPG){ sl = es[e] & 255; dl = ed[e] & 255; }
    else { sl = dl = e - EPG; }
    int r = dl - lo;
    if ((unsigned)r < 128u){
      int p = atomicAdd(&cnt_s[r], 1);
      if (p < CAP) src_s[p] = (unsigned char)sl;
    }
  }
  __syncthreads();

  // ---- scores
  const int s0 = start_s[pairi];
  int sE = s0 + deg_s[pairi];
  if (sE > CAP) sE = CAP;
  float smax = -3.0e38f;
  for (int idx = s0; idx < sE; idx++){
    int sl = src_s[idx];
    float sc = 0.f;
    int base = sl * 17 + sub * 8;
#pragma unroll
    for (int c = 0; c < 8; c++){
      f16x2 a = xl_s[base + c];
      float t0 = (float)a.x + xrv[2 * c];
      float t1 = (float)a.y + xrv[2 * c + 1];
      float l0 = fmaxf(t0, 0.2f * t0);
      float l1 = fmaxf(t1, 0.2f * t1);
      sc = fmaf(l0, attv[2 * c], sc);
      sc = fmaf(l1, attv[2 * c + 1], sc);
    }
    sc += __shfl_xor(sc, 1, 64);
    if (sub == 0) sc_s[idx] = sc;
    smax = fmaxf(smax, sc);
  }
  float ssum = 0.f;
  for (int idx = s0; idx < sE; idx++){
    float w = __expf(sc_s[idx] - smax);
    ssum += w;
    if (sub == 0) sc_s[idx] = w;
  }
  float inv = 1.f / ssum;
  float acc[16];
#pragma unroll
  for (int c = 0; c < 16; c++) acc[c] = 0.f;
  for (int idx = s0; idx < sE; idx++){
    int sl = src_s[idx];
    float w = sc_s[idx];
    int base = sl * 17 + sub * 8;
#pragma unroll
    for (int c = 0; c < 8; c++){
      f16x2 a = xl_s[base + c];
      acc[2 * c] = fmaf(w, (float)a.x, acc[2 * c]);
      acc[2 * c + 1] = fmaf(w, (float)a.y, acc[2 * c + 1]);
    }
  }
  f16x2* orow = hout + (size_t)(gs * 256 + ln) * 16 + sub * 8;
#pragma unroll
  for (int c = 0; c < 8; c++){
    float v0 = acc[2 * c] * inv + bias[sub * 16 + 2 * c];
    float v1 = acc[2 * c + 1] * inv + bias[sub * 16 + 2 * c + 1];
    f16x2 p; p.x = (f16)v0; p.y = (f16)v1;
    orow[c] = p;
  }
}

// ---------------- sim + InstanceNorm + collapsed Sinkhorn + output
// grid 64 (one block per batch), 256 threads: thread t owns sim column t.
__global__ __launch_bounds__(256) void simtopk(
    const f16x2* __restrict__ hfin,
    const float* __restrict__ gamma, const float* __restrict__ beta,
    float* __restrict__ out)
{
  __shared__ float h1f[256 * 32];
  __shared__ f16x2 h2h[256 * 16];
  __shared__ float rbuf[4];

  const int b = blockIdx.x, t = threadIdx.x;
  const f16x2* p1 = hfin + (size_t)b * 256 * 16;
  const f16x2* p2 = hfin + (size_t)(64 + b) * 256 * 16;
  for (int idx = t; idx < 256 * 16; idx += 256){
    f16x2 v = p1[idx];
    h1f[2 * idx] = (float)v.x;
    h1f[2 * idx + 1] = (float)v.y;
    h2h[idx] = p2[idx];
  }
  __syncthreads();

  float c2[32];
#pragma unroll
  for (int c = 0; c < 16; c++){
    f16x2 v = h2h[t * 16 + c];
    c2[2 * c] = (float)v.x;
    c2[2 * c + 1] = (float)v.y;
  }

  float* simc = out + (size_t)b * 65536;
  float mn = 3.0e38f, mx = -3.0e38f, sm = 0.f, s2 = 0.f;
  for (int i = 0; i < 256; i++){
    float s = 0.f;
    const float* hrow = &h1f[i * 32];
#pragma unroll
    for (int k = 0; k < 32; k++) s = fmaf(hrow[k], c2[k], s);
    mn = fminf(mn, s); mx = fmaxf(mx, s);
    sm += s; s2 = fmaf(s, s, s2);
    simc[i * 256 + t] = s;
  }

  sm = blk_sum(sm, rbuf);
  s2 = blk_sum(s2, rbuf);
  mn = blk_min(mn, rbuf);
  mx = blk_max(mx, rbuf);

  // InstanceNorm affine: sn = a*s + cc ;  d0 = 2*sn - mnn - mxn (TAU=1)
  const float mu = sm * (1.f / 65536.f);
  const float var = s2 * (1.f / 65536.f) - mu * mu;
  const float a = gamma[0] * rsqrtf(var + 1e-5f);
  const float cc = beta[0] - a * mu;
  float mnn = a * mn + cc, mxn = a * mx + cc;
  if (a < 0.f){ float tmp = mnn; mnn = mxn; mxn = tmp; }
  const float al = 2.f * a;
  const float be = 2.f * cc - mnn - mxn;

  // collapsed Sinkhorn: 5 (row,col) pairs -> 5 sigmoid-sum reductions
  float D = 0.f, S = 1.f;
  for (int p = 0; p < 5; p++){
    float loc = 0.f;
    for (int i = 0; i < 256; i++){
      float s = simc[i * 256 + t];
      float z = fmaf(al, s, be) + D;
      loc += 1.f / (1.f + __expf(-z));
    }
    S = blk_sum(loc, rbuf);
    if (p < 4) D += -5.5412635f /* log(256/65280) */ + __logf(65536.f - S) - __logf(S);
  }

  const float scale = 256.f / S;
  for (int i = 0; i < 256; i++){
    float s = simc[i * 256 + t];
    float z = fmaf(al, s, be) + D;
    float v = scale / (1.f + __expf(-z));
    simc[i * 256 + t] = fminf(v, 1.f);
  }
}

extern "C" void kernel_launch(void* const* d_in, const int* in_sizes, int n_in,
                              void* d_out, int out_size, void* d_ws, size_t ws_size,
                              hipStream_t stream)
{
  const float* x1   = (const float*)d_in[0];
  const float* x2   = (const float*)d_in[1];
  const int*   e1   = (const int*)d_in[2];
  const int*   e2   = (const int*)d_in[3];
  const float* Wl1  = (const float*)d_in[4];
  const float* Wr1  = (const float*)d_in[5];
  const float* bl1  = (const float*)d_in[6];
  const float* br1  = (const float*)d_in[7];
  const float* att1 = (const float*)d_in[8];
  const float* bias1= (const float*)d_in[9];
  const float* Wl2  = (const float*)d_in[10];
  const float* Wr2  = (const float*)d_in[11];
  const float* bl2  = (const float*)d_in[12];
  const float* br2  = (const float*)d_in[13];
  const float* att2 = (const float*)d_in[14];
  const float* bias2= (const float*)d_in[15];
  const float* gamma= (const float*)d_in[16];
  const float* beta = (const float*)d_in[17];

  f16x2* hmid = (f16x2*)d_ws;                                   // 128*256*32 f16x2 = 4 MB
  f16x2* hfin = (f16x2*)((char*)d_ws + (size_t)4 * 1024 * 1024);// 128*256*16 f16x2 = 2 MB
  float* out = (float*)d_out;

  gat1<<<256, 256, 0, stream>>>(x1, x2, e1, e2, Wl1, Wr1, bl1, br1, att1, bias1, hmid);
  gat2<<<256, 256, 0, stream>>>(e1, e2, hmid, Wl2, Wr2, bl2, br2, att2, bias2, hfin);
  simtopk<<<64, 256, 0, stream>>>(hfin, gamma, beta, out);
}

// Round 2
// 271.202 us; speedup vs baseline: 1.4527x; 1.4527x over previous
//
#include <hip/hip_runtime.h>

#define NB 64
#define NN 256
#define IND 7
#define HIDD 64
#define OUTD 32
#define EPG 8192
#define ETOT 524288
#define CAP 5500      // CSR capacity per half-graph (mean 4224)

typedef _Float16 f16;
typedef f16 f16x2 __attribute__((ext_vector_type(2)));
typedef f16 f16x8 __attribute__((ext_vector_type(8)));
typedef float f32x4 __attribute__((ext_vector_type(4)));

// ---------------- block reductions for 16-wave blocks (rb: >=16 floats) ----
__device__ __forceinline__ float bsum16(float v, float* rb){
#pragma unroll
  for (int o = 32; o > 0; o >>= 1) v += __shfl_xor(v, o, 64);
  __syncthreads();
  if ((threadIdx.x & 63) == 0) rb[threadIdx.x >> 6] = v;
  __syncthreads();
  float s = 0.f;
#pragma unroll
  for (int i = 0; i < 16; i++) s += rb[i];
  return s;
}
__device__ __forceinline__ float bmin16(float v, float* rb){
#pragma unroll
  for (int o = 32; o > 0; o >>= 1) v = fminf(v, __shfl_xor(v, o, 64));
  __syncthreads();
  if ((threadIdx.x & 63) == 0) rb[threadIdx.x >> 6] = v;
  __syncthreads();
  float s = rb[0];
#pragma unroll
  for (int i = 1; i < 16; i++) s = fminf(s, rb[i]);
  return s;
}
__device__ __forceinline__ float bmax16(float v, float* rb){
#pragma unroll
  for (int o = 32; o > 0; o >>= 1) v = fmaxf(v, __shfl_xor(v, o, 64));
  __syncthreads();
  if ((threadIdx.x & 63) == 0) rb[threadIdx.x >> 6] = v;
  __syncthreads();
  float s = rb[0];
#pragma unroll
  for (int i = 1; i < 16; i++) s = fmaxf(s, rb[i]);
  return s;
}

// ---------------- GAT layer 1 ----------------
// grid 256: block = (graph-side gs=bid>>1, dst-half=bid&1), 512 threads, 4/dst.
__global__ __launch_bounds__(512) void gat1(
    const float* __restrict__ x1, const float* __restrict__ x2,
    const int* __restrict__ e1, const int* __restrict__ e2,
    const float* __restrict__ Wl, const float* __restrict__ Wr,
    const float* __restrict__ bl, const float* __restrict__ br,
    const float* __restrict__ att, const float* __restrict__ bias,
    f16x2* __restrict__ hmid)
{
  __shared__ f16x2 xl_s[256 * 33];
  __shared__ float sc_s[CAP];
  __shared__ unsigned char src_s[CAP];
  __shared__ int deg_s[128], start_s[128], cnt_s[128];
  __shared__ int wavesum[8];

  const int bid = blockIdx.x;
  const int gs = bid >> 1, half = bid & 1;
  const int side = gs >> 6, g = gs & 63;
  const float* x = side ? x2 : x1;
  const int* eb = side ? e2 : e1;
  const int* es = eb + g * EPG;
  const int* ed = eb + ETOT + g * EPG;
  const int lo = half * 128;
  const int t = threadIdx.x;

  // ---- xl = x@Wl + bl: thread t handles node t>>1, dim-half t&1 (32 dims)
  {
    const int node = t >> 1, dh = t & 1;
    float xv[IND];
    const float* xr_ = x + (g * 256 + node) * IND;
#pragma unroll
    for (int k = 0; k < IND; k++) xv[k] = xr_[k];
#pragma unroll
    for (int d = 0; d < 32; d += 2){
      int dd = dh * 32 + d;
      float a0 = bl[dd], a1 = bl[dd + 1];
#pragma unroll
      for (int k = 0; k < IND; k++){
        a0 = fmaf(xv[k], Wl[k * HIDD + dd], a0);
        a1 = fmaf(xv[k], Wl[k * HIDD + dd + 1], a1);
      }
      f16x2 p; p.x = (f16)a0; p.y = (f16)a1;
      xl_s[node * 33 + dh * 16 + (d >> 1)] = p;
    }
  }

  // ---- 4 threads/dst: xr chunk (16 dims) + att chunk
  const int pairi = t >> 2, sub = t & 3, ln = lo + pairi;
  float xrv[16], attv[16];
  {
    float xv[IND];
    const float* xq = x + (g * 256 + ln) * IND;
#pragma unroll
    for (int k = 0; k < IND; k++) xv[k] = xq[k];
#pragma unroll
    for (int d = 0; d < 16; d++){
      int dd = sub * 16 + d;
      float a = br[dd];
#pragma unroll
      for (int k = 0; k < IND; k++) a = fmaf(xv[k], Wr[k * HIDD + dd], a);
      xrv[d] = a;
      attv[d] = att[dd];
    }
  }

  // ---- CSR build
  if (t < 128) deg_s[t] = 0;
  __syncthreads();
  for (int e = t; e < EPG + 256; e += 512){
    int dl = (e < EPG) ? (ed[e] & 255) : (e - EPG);
    int r = dl - lo;
    if ((unsigned)r < 128u) atomicAdd(&deg_s[r], 1);
  }
  __syncthreads();
  {
    int v = (t < 128) ? deg_s[t] : 0;
    int lane = t & 63, wid = t >> 6;
    int s = v;
#pragma unroll
    for (int off = 1; off < 64; off <<= 1){
      int u = __shfl_up(s, off, 64);
      if (lane >= off) s += u;
    }
    if (lane == 63) wavesum[wid] = s;
    __syncthreads();
    if (t < 128){
      int o = (wid == 1) ? wavesum[0] : 0;
      start_s[t] = s - v + o;
      cnt_s[t] = s - v + o;
    }
  }
  __syncthreads();
  for (int e = t; e < EPG + 256; e += 512){
    int sl, dl;
    if (e < EPG){ sl = es[e] & 255; dl = ed[e] & 255; }
    else { sl = dl = e - EPG; }
    int r = dl - lo;
    if ((unsigned)r < 128u){
      int p = atomicAdd(&cnt_s[r], 1);
      if (p < CAP) src_s[p] = (unsigned char)sl;
    }
  }
  __syncthreads();

  // ---- scores
  const int s0 = start_s[pairi];
  int sE = s0 + deg_s[pairi];
  if (sE > CAP) sE = CAP;
  float smax = -3.0e38f;
  int sl = (s0 < sE) ? src_s[s0] : 0;
  for (int idx = s0; idx < sE; idx++){
    int sln = (idx + 1 < sE) ? src_s[idx + 1] : 0;
    float sc = 0.f;
    int base = sl * 33 + sub * 8;
#pragma unroll
    for (int c = 0; c < 8; c++){
      f16x2 a = xl_s[base + c];
      float t0 = (float)a.x + xrv[2 * c];
      float t1 = (float)a.y + xrv[2 * c + 1];
      float l0 = fmaxf(t0, 0.2f * t0);
      float l1 = fmaxf(t1, 0.2f * t1);
      sc = fmaf(l0, attv[2 * c], sc);
      sc = fmaf(l1, attv[2 * c + 1], sc);
    }
    sc += __shfl_xor(sc, 1, 64);
    sc += __shfl_xor(sc, 2, 64);
    if (sub == 0) sc_s[idx] = sc;
    smax = fmaxf(smax, sc);
    sl = sln;
  }
  // ---- softmax weights
  float ssum = 0.f;
  for (int idx = s0; idx < sE; idx++){
    float w = __expf(sc_s[idx] - smax);
    ssum += w;
    if (sub == 0) sc_s[idx] = w;
  }
  float inv = 1.f / ssum;
  // ---- aggregate
  float acc[16];
#pragma unroll
  for (int c = 0; c < 16; c++) acc[c] = 0.f;
  sl = (s0 < sE) ? src_s[s0] : 0;
  for (int idx = s0; idx < sE; idx++){
    int sln = (idx + 1 < sE) ? src_s[idx + 1] : 0;
    float w = sc_s[idx];
    int base = sl * 33 + sub * 8;
#pragma unroll
    for (int c = 0; c < 8; c++){
      f16x2 a = xl_s[base + c];
      acc[2 * c] = fmaf(w, (float)a.x, acc[2 * c]);
      acc[2 * c + 1] = fmaf(w, (float)a.y, acc[2 * c + 1]);
    }
    sl = sln;
  }
  f16x2* orow = hmid + (size_t)(gs * 256 + ln) * 32 + sub * 8;
#pragma unroll
  for (int c = 0; c < 8; c++){
    float v0 = fmaxf(acc[2 * c] * inv + bias[sub * 16 + 2 * c], 0.f);
    float v1 = fmaxf(acc[2 * c + 1] * inv + bias[sub * 16 + 2 * c + 1], 0.f);
    f16x2 p; p.x = (f16)v0; p.y = (f16)v1;
    orow[c] = p;
  }
}

// ---------------- GAT layer 2 ----------------
__global__ __launch_bounds__(512) void gat2(
    const int* __restrict__ e1, const int* __restrict__ e2,
    const f16x2* __restrict__ hmid,
    const float* __restrict__ Wl, const float* __restrict__ Wr,
    const float* __restrict__ bl, const float* __restrict__ br,
    const float* __restrict__ att, const float* __restrict__ bias,
    f16x2* __restrict__ hout)
{
  __shared__ f16x2 xl_s[256 * 17];
  __shared__ float sc_s[CAP];
  __shared__ unsigned char src_s[CAP];
  __shared__ int deg_s[128], start_s[128], cnt_s[128];
  __shared__ int wavesum[8];

  const int bid = blockIdx.x;
  const int gs = bid >> 1, half = bid & 1;
  const int side = gs >> 6, g = gs & 63;
  const int* eb = side ? e2 : e1;
  const int* es = eb + g * EPG;
  const int* ed = eb + ETOT + g * EPG;
  const int lo = half * 128;
  const int t = threadIdx.x;

  // ---- xl2: thread t -> node t>>1, dim-half t&1 (16 dims)
  {
    const int node = t >> 1, dh = t & 1;
    const f16x2* hr = hmid + (size_t)(gs * 256 + node) * 32;
    float acc[16];
#pragma unroll
    for (int d = 0; d < 16; d++) acc[d] = bl[dh * 16 + d];
    for (int k = 0; k < 64; k += 2){
      f16x2 hp = hr[k >> 1];
      float h0 = (float)hp.x, h1 = (float)hp.y;
#pragma unroll
      for (int d = 0; d < 16; d++){
        acc[d] = fmaf(h0, Wl[k * 32 + dh * 16 + d], acc[d]);
        acc[d] = fmaf(h1, Wl[(k + 1) * 32 + dh * 16 + d], acc[d]);
      }
    }
#pragma unroll
    for (int d = 0; d < 16; d += 2){
      f16x2 p; p.x = (f16)acc[d]; p.y = (f16)acc[d + 1];
      xl_s[node * 17 + dh * 8 + (d >> 1)] = p;
    }
  }

  // ---- 4 threads/dst: xr2 chunk (8 dims)
  const int pairi = t >> 2, sub = t & 3, ln = lo + pairi;
  float xrv[8], attv[8];
  {
    const f16x2* hr = hmid + (size_t)(gs * 256 + ln) * 32;
    float acc[8];
#pragma unroll
    for (int d = 0; d < 8; d++) acc[d] = br[sub * 8 + d];
    for (int k = 0; k < 64; k += 2){
      f16x2 hp = hr[k >> 1];
      float h0 = (float)hp.x, h1 = (float)hp.y;
#pragma unroll
      for (int d = 0; d < 8; d++){
        acc[d] = fmaf(h0, Wr[k * 32 + sub * 8 + d], acc[d]);
        acc[d] = fmaf(h1, Wr[(k + 1) * 32 + sub * 8 + d], acc[d]);
      }
    }
#pragma unroll
    for (int d = 0; d < 8; d++){ xrv[d] = acc[d]; attv[d] = att[sub * 8 + d]; }
  }

  // ---- CSR build
  if (t < 128) deg_s[t] = 0;
  __syncthreads();
  for (int e = t; e < EPG + 256; e += 512){
    int dl = (e < EPG) ? (ed[e] & 255) : (e - EPG);
    int r = dl - lo;
    if ((unsigned)r < 128u) atomicAdd(&deg_s[r], 1);
  }
  __syncthreads();
  {
    int v = (t < 128) ? deg_s[t] : 0;
    int lane = t & 63, wid = t >> 6;
    int s = v;
#pragma unroll
    for (int off = 1; off < 64; off <<= 1){
      int u = __shfl_up(s, off, 64);
      if (lane >= off) s += u;
    }
    if (lane == 63) wavesum[wid] = s;
    __syncthreads();
    if (t < 128){
      int o = (wid == 1) ? wavesum[0] : 0;
      start_s[t] = s - v + o;
      cnt_s[t] = s - v + o;
    }
  }
  __syncthreads();
  for (int e = t; e < EPG + 256; e += 512){
    int sl, dl;
    if (e < EPG){ sl = es[e] & 255; dl = ed[e] & 255; }
    else { sl = dl = e - EPG; }
    int r = dl - lo;
    if ((unsigned)r < 128u){
      int p = atomicAdd(&cnt_s[r], 1);
      if (p < CAP) src_s[p] = (unsigned char)sl;
    }
  }
  __syncthreads();

  // ---- scores
  const int s0 = start_s[pairi];
  int sE = s0 + deg_s[pairi];
  if (sE > CAP) sE = CAP;
  float smax = -3.0e38f;
  int sl = (s0 < sE) ? src_s[s0] : 0;
  for (int idx = s0; idx < sE; idx++){
    int sln = (idx + 1 < sE) ? src_s[idx + 1] : 0;
    float sc = 0.f;
    int base = sl * 17 + sub * 4;
#pragma unroll
    for (int c = 0; c < 4; c++){
      f16x2 a = xl_s[base + c];
      float t0 = (float)a.x + xrv[2 * c];
      float t1 = (float)a.y + xrv[2 * c + 1];
      float l0 = fmaxf(t0, 0.2f * t0);
      float l1 = fmaxf(t1, 0.2f * t1);
      sc = fmaf(l0, attv[2 * c], sc);
      sc = fmaf(l1, attv[2 * c + 1], sc);
    }
    sc += __shfl_xor(sc, 1, 64);
    sc += __shfl_xor(sc, 2, 64);
    if (sub == 0) sc_s[idx] = sc;
    smax = fmaxf(smax, sc);
    sl = sln;
  }
  float ssum = 0.f;
  for (int idx = s0; idx < sE; idx++){
    float w = __expf(sc_s[idx] - smax);
    ssum += w;
    if (sub == 0) sc_s[idx] = w;
  }
  float inv = 1.f / ssum;
  float acc[8];
#pragma unroll
  for (int c = 0; c < 8; c++) acc[c] = 0.f;
  sl = (s0 < sE) ? src_s[s0] : 0;
  for (int idx = s0; idx < sE; idx++){
    int sln = (idx + 1 < sE) ? src_s[idx + 1] : 0;
    float w = sc_s[idx];
    int base = sl * 17 + sub * 4;
#pragma unroll
    for (int c = 0; c < 4; c++){
      f16x2 a = xl_s[base + c];
      acc[2 * c] = fmaf(w, (float)a.x, acc[2 * c]);
      acc[2 * c + 1] = fmaf(w, (float)a.y, acc[2 * c + 1]);
    }
    sl = sln;
  }
  f16x2* orow = hout + (size_t)(gs * 256 + ln) * 16 + sub * 4;
#pragma unroll
  for (int c = 0; c < 4; c++){
    float v0 = acc[2 * c] * inv + bias[sub * 8 + 2 * c];
    float v1 = acc[2 * c + 1] * inv + bias[sub * 8 + 2 * c + 1];
    f16x2 p; p.x = (f16)v0; p.y = (f16)v1;
    orow[c] = p;
  }
}

// ---------------- sim (MFMA) + InstanceNorm + collapsed Sinkhorn -----------
// grid 64, 1024 threads (16 waves). Wave w: sim rows [w*16, w*16+16), all cols,
// as 16 mfma_f32_16x16x32_f16 tiles. Sinkhorn runs on the accumulator regs.
__global__ __launch_bounds__(1024) void simtopk(
    const f16* __restrict__ H,
    const float* __restrict__ gamma, const float* __restrict__ beta,
    float* __restrict__ out)
{
  __shared__ float rb[16];
  const int b = blockIdx.x, t = threadIdx.x;
  const int w = t >> 6, lane = t & 63;
  const int m = lane & 15, quad = lane >> 4;

  const f16* h1 = H + (size_t)b * 256 * 32;
  const f16* h2 = H + (size_t)(64 + b) * 256 * 32;

  // A-frag: rows w*16+m of h1, k = quad*8..quad*8+7 (contiguous 16B)
  f16x8 av = *(const f16x8*)(h1 + (size_t)(w * 16 + m) * 32 + quad * 8);
  f32x4 c[16];
#pragma unroll
  for (int j = 0; j < 16; j++){
    f16x8 bv = *(const f16x8*)(h2 + (size_t)(j * 16 + m) * 32 + quad * 8);
    f32x4 z = {0.f, 0.f, 0.f, 0.f};
    c[j] = __builtin_amdgcn_mfma_f32_16x16x32_f16(av, bv, z, 0, 0, 0);
  }

  // ---- InstanceNorm stats over all 64 reg-resident sim values
  float sm = 0.f, s2 = 0.f, mn = 3.0e38f, mx = -3.0e38f;
#pragma unroll
  for (int j = 0; j < 16; j++)
#pragma unroll
    for (int r = 0; r < 4; r++){
      float s = c[j][r];
      sm += s; s2 = fmaf(s, s, s2);
      mn = fminf(mn, s); mx = fmaxf(mx, s);
    }
  sm = bsum16(sm, rb);
  s2 = bsum16(s2, rb);
  mn = bmin16(mn, rb);
  mx = bmax16(mx, rb);

  const float mu = sm * (1.f / 65536.f);
  const float var = s2 * (1.f / 65536.f) - mu * mu;
  const float a = gamma[0] * rsqrtf(var + 1e-5f);
  const float cc = beta[0] - a * mu;
  float mnn = a * mn + cc, mxn = a * mx + cc;
  if (a < 0.f){ float tmp = mnn; mnn = mxn; mxn = tmp; }
  const float al = 2.f * a;
  const float be = 2.f * cc - mnn - mxn;

  // z-base into the acc regs
#pragma unroll
  for (int j = 0; j < 16; j++)
#pragma unroll
    for (int r = 0; r < 4; r++)
      c[j][r] = fmaf(al, c[j][r], be);

  // collapsed Sinkhorn: 5 sigmoid-sum reductions
  float D = 0.f, S = 1.f;
  for (int p = 0; p < 5; p++){
    float loc = 0.f;
#pragma unroll
    for (int j = 0; j < 16; j++)
#pragma unroll
      for (int r = 0; r < 4; r++){
        float z = c[j][r] + D;
        loc += 1.f / (1.f + __expf(-z));
      }
    S = bsum16(loc, rb);
    if (p < 4) D += -5.5412635f /* log(256/65280) */ + __logf(65536.f - S) - __logf(S);
  }

  const float scale = 256.f / S;
  float* ob = out + (size_t)b * 65536;
#pragma unroll
  for (int j = 0; j < 16; j++){
#pragma unroll
    for (int r = 0; r < 4; r++){
      float v = scale / (1.f + __expf(-(c[j][r] + D)));
      int row = w * 16 + quad * 4 + r;
      int col = j * 16 + m;
      ob[row * 256 + col] = fminf(v, 1.f);
    }
  }
}

extern "C" void kernel_launch(void* const* d_in, const int* in_sizes, int n_in,
                              void* d_out, int out_size, void* d_ws, size_t ws_size,
                              hipStream_t stream)
{
  const float* x1   = (const float*)d_in[0];
  const float* x2   = (const float*)d_in[1];
  const int*   e1   = (const int*)d_in[2];
  const int*   e2   = (const int*)d_in[3];
  const float* Wl1  = (const float*)d_in[4];
  const float* Wr1  = (const float*)d_in[5];
  const float* bl1  = (const float*)d_in[6];
  const float* br1  = (const float*)d_in[7];
  const float* att1 = (const float*)d_in[8];
  const float* bias1= (const float*)d_in[9];
  const float* Wl2  = (const float*)d_in[10];
  const float* Wr2  = (const float*)d_in[11];
  const float* bl2  = (const float*)d_in[12];
  const float* br2  = (const float*)d_in[13];
  const float* att2 = (const float*)d_in[14];
  const float* bias2= (const float*)d_in[15];
  const float* gamma= (const float*)d_in[16];
  const float* beta = (const float*)d_in[17];

  f16x2* hmid = (f16x2*)d_ws;                                   // 128*256*32 f16x2 = 4 MB
  f16x2* hfin = (f16x2*)((char*)d_ws + (size_t)4 * 1024 * 1024);// 128*256*16 f16x2 = 2 MB
  float* out = (float*)d_out;

  gat1<<<256, 512, 0, stream>>>(x1, x2, e1, e2, Wl1, Wr1, bl1, br1, att1, bias1, hmid);
  gat2<<<256, 512, 0, stream>>>(e1, e2, hmid, Wl2, Wr2, bl2, br2, att2, bias2, hfin);
  simtopk<<<64, 1024, 0, stream>>>((const f16*)hfin, gamma, beta, out);
}

// Round 4
// 247.824 us; speedup vs baseline: 1.5897x; 1.0943x over previous
//
#include <hip/hip_runtime.h>

#define NB 64
#define NN 256
#define IND 7
#define HIDD 64
#define OUTD 32
#define EPG 8192
#define ETOT 524288
#define CAPQ 2600     // CSR capacity per 64-dst quarter (mean 2112, ~12 sigma)

typedef _Float16 f16;
typedef f16 f16x2 __attribute__((ext_vector_type(2)));
typedef f16 f16x4 __attribute__((ext_vector_type(4)));
typedef f16 f16x8 __attribute__((ext_vector_type(8)));
typedef float f32x4 __attribute__((ext_vector_type(4)));

// ---------------- block reductions for 16-wave blocks ----------------
__device__ __forceinline__ float bsum16(float v, float* rb){
#pragma unroll
  for (int o = 32; o > 0; o >>= 1) v += __shfl_xor(v, o, 64);
  __syncthreads();
  if ((threadIdx.x & 63) == 0) rb[threadIdx.x >> 6] = v;
  __syncthreads();
  float s = 0.f;
#pragma unroll
  for (int i = 0; i < 16; i++) s += rb[i];
  return s;
}
__device__ __forceinline__ float bmin16(float v, float* rb){
#pragma unroll
  for (int o = 32; o > 0; o >>= 1) v = fminf(v, __shfl_xor(v, o, 64));
  __syncthreads();
  if ((threadIdx.x & 63) == 0) rb[threadIdx.x >> 6] = v;
  __syncthreads();
  float s = rb[0];
#pragma unroll
  for (int i = 1; i < 16; i++) s = fminf(s, rb[i]);
  return s;
}
__device__ __forceinline__ float bmax16(float v, float* rb){
#pragma unroll
  for (int o = 32; o > 0; o >>= 1) v = fmaxf(v, __shfl_xor(v, o, 64));
  __syncthreads();
  if ((threadIdx.x & 63) == 0) rb[threadIdx.x >> 6] = v;
  __syncthreads();
  float s = rb[0];
#pragma unroll
  for (int i = 1; i < 16; i++) s = fmaxf(s, rb[i]);
  return s;
}

__device__ __forceinline__ f16x2 lrelu2(f16x2 s){
  const f16x2 k = {(f16)0.2f, (f16)0.2f};
  return __builtin_elementwise_max(s, s * k);
}

// ---------------- GAT layer 1 ----------------
// grid 512: (graph-side gs=bid>>2, quarter=bid&3 -> 64 dsts), 512 thr, 8/dst.
__global__ __launch_bounds__(512) void gat1(
    const float* __restrict__ x1, const float* __restrict__ x2,
    const int* __restrict__ e1, const int* __restrict__ e2,
    const float* __restrict__ Wl, const float* __restrict__ Wr,
    const float* __restrict__ bl, const float* __restrict__ br,
    const float* __restrict__ att, const float* __restrict__ bias,
    f16* __restrict__ hmid)
{
  __shared__ __align__(16) f16 xl_s[256 * 72];   // rows padded to 144B
  __shared__ float sc_s[CAPQ];
  __shared__ unsigned char src_s[CAPQ];
  __shared__ int deg_s[64], start_s[64], cnt_s[64];

  const int bid = blockIdx.x;
  const int gs = bid >> 2, lo = (bid & 3) * 64;
  const int side = gs >> 6, g = gs & 63;
  const float* x = side ? x2 : x1;
  const int* eb = side ? e2 : e1;
  const int* es = eb + g * EPG;
  const int* ed = eb + ETOT + g * EPG;
  const int t = threadIdx.x;

  // ---- xl = x@Wl + bl: thread t -> node t>>1, dim-half t&1 (32 dims), f16 LDS
  {
    const int node = t >> 1, dh = t & 1;
    float xv[IND];
    const float* xr_ = x + (g * 256 + node) * IND;
#pragma unroll
    for (int k = 0; k < IND; k++) xv[k] = xr_[k];
#pragma unroll
    for (int ch = 0; ch < 4; ch++){
      f16x8 o;
#pragma unroll
      for (int j = 0; j < 8; j++){
        int dd = dh * 32 + ch * 8 + j;
        float a = bl[dd];
#pragma unroll
        for (int k = 0; k < IND; k++) a = fmaf(xv[k], Wl[k * HIDD + dd], a);
        o[j] = (f16)a;
      }
      *(f16x8*)&xl_s[node * 72 + dh * 32 + ch * 8] = o;
    }
  }

  // ---- 8 threads/dst: xr chunk (8 dims, f16) + att chunk
  const int pairi = t >> 3, sub = t & 7, ln = lo + pairi;
  f16x2 xrh[4], atth[4];
  {
    float xv[IND];
    const float* xq = x + (g * 256 + ln) * IND;
#pragma unroll
    for (int k = 0; k < IND; k++) xv[k] = xq[k];
#pragma unroll
    for (int c = 0; c < 4; c++){
#pragma unroll
      for (int u = 0; u < 2; u++){
        int dd = sub * 8 + 2 * c + u;
        float a = br[dd];
#pragma unroll
        for (int k = 0; k < IND; k++) a = fmaf(xv[k], Wr[k * HIDD + dd], a);
        xrh[c][u] = (f16)a;
        atth[c][u] = (f16)att[dd];
      }
    }
  }

  // ---- CSR build over this quarter's 64 dsts
  if (t < 64) deg_s[t] = 0;
  __syncthreads();
  for (int e = t; e < EPG + 256; e += 512){
    int dl = (e < EPG) ? (ed[e] & 255) : (e - EPG);
    int r = dl - lo;
    if ((unsigned)r < 64u) atomicAdd(&deg_s[r], 1);
  }
  __syncthreads();
  if (t < 64){
    int v = deg_s[t], s = v;
#pragma unroll
    for (int off = 1; off < 64; off <<= 1){
      int u = __shfl_up(s, off, 64);
      if (t >= off) s += u;
    }
    start_s[t] = s - v;
    cnt_s[t] = s - v;
  }
  __syncthreads();
  for (int e = t; e < EPG + 256; e += 512){
    int sl, dl;
    if (e < EPG){ sl = es[e] & 255; dl = ed[e] & 255; }
    else { sl = dl = e - EPG; }
    int r = dl - lo;
    if ((unsigned)r < 64u){
      int p = atomicAdd(&cnt_s[r], 1);
      if (p < CAPQ) src_s[p] = (unsigned char)sl;
    }
  }
  __syncthreads();

  // ---- scores: dim-split 8 ways, combine via 3 shfl; prefetch next row
  const int s0 = start_s[pairi];
  int sE = s0 + deg_s[pairi];
  if (sE > CAPQ) sE = CAPQ;
  float smax = -3.0e38f;
  {
    int sl = (s0 < sE) ? src_s[s0] : 0;
    f16x8 row = *(const f16x8*)&xl_s[sl * 72 + sub * 8];
    for (int idx = s0; idx < sE; idx++){
      int sln = (idx + 1 < sE) ? src_s[idx + 1] : 0;
      f16x8 rown = *(const f16x8*)&xl_s[sln * 72 + sub * 8];
      f16x2 r0 = {row[0], row[1]}, r1 = {row[2], row[3]};
      f16x2 r2 = {row[4], row[5]}, r3 = {row[6], row[7]};
      float sc = __builtin_amdgcn_fdot2(lrelu2(r0 + xrh[0]), atth[0], 0.f, false);
      sc = __builtin_amdgcn_fdot2(lrelu2(r1 + xrh[1]), atth[1], sc, false);
      sc = __builtin_amdgcn_fdot2(lrelu2(r2 + xrh[2]), atth[2], sc, false);
      sc = __builtin_amdgcn_fdot2(lrelu2(r3 + xrh[3]), atth[3], sc, false);
      sc += __shfl_xor(sc, 1, 64);
      sc += __shfl_xor(sc, 2, 64);
      sc += __shfl_xor(sc, 4, 64);
      if (sub == 0) sc_s[idx] = sc;
      smax = fmaxf(smax, sc);
      row = rown;
    }
  }
  // ---- softmax weights: each sub handles every-8th edge, reduce sum
  float ssum = 0.f;
  for (int idx = s0 + sub; idx < sE; idx += 8){
    float w = __expf(sc_s[idx] - smax);
    ssum += w;
    sc_s[idx] = w;
  }
  ssum += __shfl_xor(ssum, 1, 64);
  ssum += __shfl_xor(ssum, 2, 64);
  ssum += __shfl_xor(ssum, 4, 64);
  float inv = 1.f / ssum;
  // ---- aggregate alpha * xl[src], dim-split 8 ways
  float acc[8];
#pragma unroll
  for (int c = 0; c < 8; c++) acc[c] = 0.f;
  {
    int sl = (s0 < sE) ? src_s[s0] : 0;
    f16x8 row = *(const f16x8*)&xl_s[sl * 72 + sub * 8];
    for (int idx = s0; idx < sE; idx++){
      int sln = (idx + 1 < sE) ? src_s[idx + 1] : 0;
      f16x8 rown = *(const f16x8*)&xl_s[sln * 72 + sub * 8];
      float w = sc_s[idx];
#pragma unroll
      for (int c = 0; c < 8; c++) acc[c] = fmaf(w, (float)row[c], acc[c]);
      row = rown;
    }
  }
  f16x8 o;
#pragma unroll
  for (int c = 0; c < 8; c++)
    o[c] = (f16)fmaxf(acc[c] * inv + bias[sub * 8 + c], 0.f);
  *(f16x8*)(hmid + (size_t)(gs * 256 + ln) * 64 + sub * 8) = o;
}

// ---------------- lin2: [32768 x 64] @ [64 x 64] (Wl2|Wr2) via MFMA --------
// grid 512 x 256 thr: block handles 64 nodes; wave w -> 16-node row tile.
__global__ __launch_bounds__(256) void lin2(
    const f16* __restrict__ hmid,
    const float* __restrict__ Wl, const float* __restrict__ Wr,
    const float* __restrict__ bl, const float* __restrict__ br,
    f16* __restrict__ xl2g, f16* __restrict__ xr2g)
{
  const int w = threadIdx.x >> 6, lane = threadIdx.x & 63;
  const int m = lane & 15, quad = lane >> 4;
  const int row0 = blockIdx.x * 64 + w * 16;

  const f16* arow = hmid + (size_t)(row0 + m) * 64;
  f16x8 a0 = *(const f16x8*)(arow + quad * 8);
  f16x8 a1 = *(const f16x8*)(arow + 32 + quad * 8);

#pragma unroll
  for (int c = 0; c < 4; c++){
    const int n = c * 16 + m;
    const float* W = (n < 32) ? Wl : Wr;
    const int nn = (n < 32) ? n : n - 32;
    f16x8 b0, b1;
#pragma unroll
    for (int j = 0; j < 8; j++){
      b0[j] = (f16)W[(quad * 8 + j) * 32 + nn];
      b1[j] = (f16)W[(32 + quad * 8 + j) * 32 + nn];
    }
    f32x4 acc = {0.f, 0.f, 0.f, 0.f};
    acc = __builtin_amdgcn_mfma_f32_16x16x32_f16(a0, b0, acc, 0, 0, 0);
    acc = __builtin_amdgcn_mfma_f32_16x16x32_f16(a1, b1, acc, 0, 0, 0);
    const float bv = (n < 32) ? bl[nn] : br[nn];
    f16* dst = (n < 32) ? xl2g : xr2g;
#pragma unroll
    for (int r = 0; r < 4; r++){
      int node = row0 + quad * 4 + r;
      dst[(size_t)node * 32 + nn] = (f16)(acc[r] + bv);
    }
  }
}

// ---------------- GAT layer 2 (transforms precomputed) ----------------
__global__ __launch_bounds__(512) void gat2(
    const int* __restrict__ e1, const int* __restrict__ e2,
    const f16* __restrict__ xl2g, const f16* __restrict__ xr2g,
    const float* __restrict__ att, const float* __restrict__ bias,
    f16* __restrict__ hout)
{
  __shared__ __align__(16) f16 xl_s[256 * 40];   // rows padded to 80B
  __shared__ float sc_s[CAPQ];
  __shared__ unsigned char src_s[CAPQ];
  __shared__ int deg_s[64], start_s[64], cnt_s[64];

  const int bid = blockIdx.x;
  const int gs = bid >> 2, lo = (bid & 3) * 64;
  const int side = gs >> 6, g = gs & 63;
  const int* eb = side ? e2 : e1;
  const int* es = eb + g * EPG;
  const int* ed = eb + ETOT + g * EPG;
  const int t = threadIdx.x;

  // ---- stage xl2 rows into padded LDS: FULL 16 f16 per thread (two f16x8)
  {
    const int node = t >> 1, dh = t & 1;
    const f16* src = xl2g + (size_t)(gs * 256 + node) * 32 + dh * 16;
    f16x8 v0 = *(const f16x8*)(src);
    f16x8 v1 = *(const f16x8*)(src + 8);
    *(f16x8*)&xl_s[node * 40 + dh * 16] = v0;
    *(f16x8*)&xl_s[node * 40 + dh * 16 + 8] = v1;
  }

  // ---- 8 threads/dst: xr2 chunk (4 dims) + att chunk
  const int pairi = t >> 3, sub = t & 7, ln = lo + pairi;
  f16x2 xrh[2], atth[2];
  {
    f16x4 v = *(const f16x4*)(xr2g + (size_t)(gs * 256 + ln) * 32 + sub * 4);
    xrh[0][0] = v[0]; xrh[0][1] = v[1]; xrh[1][0] = v[2]; xrh[1][1] = v[3];
#pragma unroll
    for (int u = 0; u < 4; u++) atth[u >> 1][u & 1] = (f16)att[sub * 4 + u];
  }

  // ---- CSR build
  if (t < 64) deg_s[t] = 0;
  __syncthreads();
  for (int e = t; e < EPG + 256; e += 512){
    int dl = (e < EPG) ? (ed[e] & 255) : (e - EPG);
    int r = dl - lo;
    if ((unsigned)r < 64u) atomicAdd(&deg_s[r], 1);
  }
  __syncthreads();
  if (t < 64){
    int v = deg_s[t], s = v;
#pragma unroll
    for (int off = 1; off < 64; off <<= 1){
      int u = __shfl_up(s, off, 64);
      if (t >= off) s += u;
    }
    start_s[t] = s - v;
    cnt_s[t] = s - v;
  }
  __syncthreads();
  for (int e = t; e < EPG + 256; e += 512){
    int sl, dl;
    if (e < EPG){ sl = es[e] & 255; dl = ed[e] & 255; }
    else { sl = dl = e - EPG; }
    int r = dl - lo;
    if ((unsigned)r < 64u){
      int p = atomicAdd(&cnt_s[r], 1);
      if (p < CAPQ) src_s[p] = (unsigned char)sl;
    }
  }
  __syncthreads();

  // ---- scores (4 dims/thread), 3-shfl combine, prefetch
  const int s0 = start_s[pairi];
  int sE = s0 + deg_s[pairi];
  if (sE > CAPQ) sE = CAPQ;
  float smax = -3.0e38f;
  {
    int sl = (s0 < sE) ? src_s[s0] : 0;
    f16x4 row = *(const f16x4*)&xl_s[sl * 40 + sub * 4];
    for (int idx = s0; idx < sE; idx++){
      int sln = (idx + 1 < sE) ? src_s[idx + 1] : 0;
      f16x4 rown = *(const f16x4*)&xl_s[sln * 40 + sub * 4];
      f16x2 r0 = {row[0], row[1]}, r1 = {row[2], row[3]};
      float sc = __builtin_amdgcn_fdot2(lrelu2(r0 + xrh[0]), atth[0], 0.f, false);
      sc = __builtin_amdgcn_fdot2(lrelu2(r1 + xrh[1]), atth[1], sc, false);
      sc += __shfl_xor(sc, 1, 64);
      sc += __shfl_xor(sc, 2, 64);
      sc += __shfl_xor(sc, 4, 64);
      if (sub == 0) sc_s[idx] = sc;
      smax = fmaxf(smax, sc);
      row = rown;
    }
  }
  float ssum = 0.f;
  for (int idx = s0 + sub; idx < sE; idx += 8){
    float w = __expf(sc_s[idx] - smax);
    ssum += w;
    sc_s[idx] = w;
  }
  ssum += __shfl_xor(ssum, 1, 64);
  ssum += __shfl_xor(ssum, 2, 64);
  ssum += __shfl_xor(ssum, 4, 64);
  float inv = 1.f / ssum;

  float acc[4];
#pragma unroll
  for (int c = 0; c < 4; c++) acc[c] = 0.f;
  {
    int sl = (s0 < sE) ? src_s[s0] : 0;
    f16x4 row = *(const f16x4*)&xl_s[sl * 40 + sub * 4];
    for (int idx = s0; idx < sE; idx++){
      int sln = (idx + 1 < sE) ? src_s[idx + 1] : 0;
      f16x4 rown = *(const f16x4*)&xl_s[sln * 40 + sub * 4];
      float w = sc_s[idx];
#pragma unroll
      for (int c = 0; c < 4; c++) acc[c] = fmaf(w, (float)row[c], acc[c]);
      row = rown;
    }
  }
  f16x4 o;
#pragma unroll
  for (int c = 0; c < 4; c++)
    o[c] = (f16)(acc[c] * inv + bias[sub * 4 + c]);
  *(f16x4*)(hout + (size_t)(gs * 256 + ln) * 32 + sub * 4) = o;
}

// ---------------- sim (MFMA) + InstanceNorm + collapsed Sinkhorn -----------
__global__ __launch_bounds__(1024) void simtopk(
    const f16* __restrict__ H,
    const float* __restrict__ gamma, const float* __restrict__ beta,
    float* __restrict__ out)
{
  __shared__ float rb[16];
  const int b = blockIdx.x, t = threadIdx.x;
  const int w = t >> 6, lane = t & 63;
  const int m = lane & 15, quad = lane >> 4;

  const f16* h1 = H + (size_t)b * 256 * 32;
  const f16* h2 = H + (size_t)(64 + b) * 256 * 32;

  f16x8 av = *(const f16x8*)(h1 + (size_t)(w * 16 + m) * 32 + quad * 8);
  f32x4 c[16];
#pragma unroll
  for (int j = 0; j < 16; j++){
    f16x8 bv = *(const f16x8*)(h2 + (size_t)(j * 16 + m) * 32 + quad * 8);
    f32x4 z = {0.f, 0.f, 0.f, 0.f};
    c[j] = __builtin_amdgcn_mfma_f32_16x16x32_f16(av, bv, z, 0, 0, 0);
  }

  float sm = 0.f, s2 = 0.f, mn = 3.0e38f, mx = -3.0e38f;
#pragma unroll
  for (int j = 0; j < 16; j++)
#pragma unroll
    for (int r = 0; r < 4; r++){
      float s = c[j][r];
      sm += s; s2 = fmaf(s, s, s2);
      mn = fminf(mn, s); mx = fmaxf(mx, s);
    }
  sm = bsum16(sm, rb);
  s2 = bsum16(s2, rb);
  mn = bmin16(mn, rb);
  mx = bmax16(mx, rb);

  const float mu = sm * (1.f / 65536.f);
  const float var = s2 * (1.f / 65536.f) - mu * mu;
  const float a = gamma[0] * rsqrtf(var + 1e-5f);
  const float cc = beta[0] - a * mu;
  float mnn = a * mn + cc, mxn = a * mx + cc;
  if (a < 0.f){ float tmp = mnn; mnn = mxn; mxn = tmp; }
  const float al = 2.f * a;
  const float be = 2.f * cc - mnn - mxn;

#pragma unroll
  for (int j = 0; j < 16; j++)
#pragma unroll
    for (int r = 0; r < 4; r++)
      c[j][r] = fmaf(al, c[j][r], be);

  float D = 0.f, S = 1.f;
  for (int p = 0; p < 5; p++){
    float loc = 0.f;
#pragma unroll
    for (int j = 0; j < 16; j++)
#pragma unroll
      for (int r = 0; r < 4; r++){
        float z = c[j][r] + D;
        loc += 1.f / (1.f + __expf(-z));
      }
    S = bsum16(loc, rb);
    if (p < 4) D += -5.5412635f + __logf(65536.f - S) - __logf(S);
  }

  const float scale = 256.f / S;
  float* ob = out + (size_t)b * 65536;
#pragma unroll
  for (int j = 0; j < 16; j++){
#pragma unroll
    for (int r = 0; r < 4; r++){
      float v = scale / (1.f + __expf(-(c[j][r] + D)));
      int row = w * 16 + quad * 4 + r;
      int col = j * 16 + m;
      ob[row * 256 + col] = fminf(v, 1.f);
    }
  }
}

extern "C" void kernel_launch(void* const* d_in, const int* in_sizes, int n_in,
                              void* d_out, int out_size, void* d_ws, size_t ws_size,
                              hipStream_t stream)
{
  const float* x1   = (const float*)d_in[0];
  const float* x2   = (const float*)d_in[1];
  const int*   e1   = (const int*)d_in[2];
  const int*   e2   = (const int*)d_in[3];
  const float* Wl1  = (const float*)d_in[4];
  const float* Wr1  = (const float*)d_in[5];
  const float* bl1  = (const float*)d_in[6];
  const float* br1  = (const float*)d_in[7];
  const float* att1 = (const float*)d_in[8];
  const float* bias1= (const float*)d_in[9];
  const float* Wl2  = (const float*)d_in[10];
  const float* Wr2  = (const float*)d_in[11];
  const float* bl2  = (const float*)d_in[12];
  const float* br2  = (const float*)d_in[13];
  const float* att2 = (const float*)d_in[14];
  const float* bias2= (const float*)d_in[15];
  const float* gamma= (const float*)d_in[16];
  const float* beta = (const float*)d_in[17];

  // ws layout (8 MB peak): hmid dead after lin2, so hfin aliases its space.
  char* ws = (char*)d_ws;
  f16* hmid = (f16*)ws;                               // [0,4MB): 128*256*64 f16
  f16* xl2g = (f16*)(ws + (size_t)4 * 1024 * 1024);   // [4,6MB)
  f16* xr2g = (f16*)(ws + (size_t)6 * 1024 * 1024);   // [6,8MB)
  f16* hfin = (f16*)(ws + (size_t)2 * 1024 * 1024);   // [2,4MB) aliases hmid tail (dead)
  float* out = (float*)d_out;

  gat1<<<512, 512, 0, stream>>>(x1, x2, e1, e2, Wl1, Wr1, bl1, br1, att1, bias1, hmid);
  lin2<<<512, 256, 0, stream>>>(hmid, Wl2, Wr2, bl2, br2, xl2g, xr2g);
  gat2<<<512, 512, 0, stream>>>(e1, e2, xl2g, xr2g, att2, bias2, hfin);
  simtopk<<<64, 1024, 0, stream>>>(hfin, gamma, beta, out);
}

// Round 5
// 209.277 us; speedup vs baseline: 1.8825x; 1.1842x over previous
//
#include <hip/hip_runtime.h>

#define NB 64
#define NN 256
#define IND 7
#define HIDD 64
#define OUTD 32
#define EPG 8192
#define ETOT 524288
#define CAPQ 2600     // CSR capacity per 64-dst quarter (mean 2112, ~12 sigma)
#define SRCPAD 2624   // CAPQ rounded to 16

typedef _Float16 f16;
typedef f16 f16x2 __attribute__((ext_vector_type(2)));
typedef f16 f16x4 __attribute__((ext_vector_type(4)));
typedef f16 f16x8 __attribute__((ext_vector_type(8)));
typedef float f32x4 __attribute__((ext_vector_type(4)));

// ---------------- block reductions for 16-wave blocks ----------------
__device__ __forceinline__ float bsum16(float v, float* rb){
#pragma unroll
  for (int o = 32; o > 0; o >>= 1) v += __shfl_xor(v, o, 64);
  __syncthreads();
  if ((threadIdx.x & 63) == 0) rb[threadIdx.x >> 6] = v;
  __syncthreads();
  float s = 0.f;
#pragma unroll
  for (int i = 0; i < 16; i++) s += rb[i];
  return s;
}
__device__ __forceinline__ float bmin16(float v, float* rb){
#pragma unroll
  for (int o = 32; o > 0; o >>= 1) v = fminf(v, __shfl_xor(v, o, 64));
  __syncthreads();
  if ((threadIdx.x & 63) == 0) rb[threadIdx.x >> 6] = v;
  __syncthreads();
  float s = rb[0];
#pragma unroll
  for (int i = 1; i < 16; i++) s = fminf(s, rb[i]);
  return s;
}
__device__ __forceinline__ float bmax16(float v, float* rb){
#pragma unroll
  for (int o = 32; o > 0; o >>= 1) v = fmaxf(v, __shfl_xor(v, o, 64));
  __syncthreads();
  if ((threadIdx.x & 63) == 0) rb[threadIdx.x >> 6] = v;
  __syncthreads();
  float s = rb[0];
#pragma unroll
  for (int i = 1; i < 16; i++) s = fmaxf(s, rb[i]);
  return s;
}

__device__ __forceinline__ f16x2 lrelu2(f16x2 s){
  const f16x2 k = {(f16)0.2f, (f16)0.2f};
  return __builtin_elementwise_max(s, s * k);
}
__device__ __forceinline__ f16x2 shfl_h2(f16x2 v, int lane){
  int i = __builtin_bit_cast(int, v);
  i = __shfl(i, lane, 64);
  return __builtin_bit_cast(f16x2, i);
}

// ---------------- csrk: build per-(graph,quarter) CSR once ----------------
// grid 512 x 256 thr. meta[bid*128+i]=start_i, meta[bid*128+64+i]=deg_i.
__global__ __launch_bounds__(256) void csrk(
    const int* __restrict__ e1, const int* __restrict__ e2,
    int* __restrict__ meta, unsigned char* __restrict__ srcs)
{
  __shared__ int deg_s[64], start_s[64], cnt_s[64];
  const int bid = blockIdx.x;
  const int gs = bid >> 2, lo = (bid & 3) * 64;
  const int side = gs >> 6, g = gs & 63;
  const int* eb = side ? e2 : e1;
  const int* es = eb + g * EPG;
  const int* ed = eb + ETOT + g * EPG;
  const int t = threadIdx.x;

  if (t < 64) deg_s[t] = 0;
  __syncthreads();
  for (int e = t; e < EPG + 256; e += 256){
    int dl = (e < EPG) ? (ed[e] & 255) : (e - EPG);
    int r = dl - lo;
    if ((unsigned)r < 64u) atomicAdd(&deg_s[r], 1);
  }
  __syncthreads();
  if (t < 64){
    int v = deg_s[t], s = v;
#pragma unroll
    for (int off = 1; off < 64; off <<= 1){
      int u = __shfl_up(s, off, 64);
      if (t >= off) s += u;
    }
    start_s[t] = s - v;
    cnt_s[t] = s - v;
    meta[bid * 128 + t] = s - v;
    meta[bid * 128 + 64 + t] = v;
  }
  __syncthreads();
  unsigned char* dst = srcs + (size_t)bid * SRCPAD;
  for (int e = t; e < EPG + 256; e += 256){
    int sl, dl;
    if (e < EPG){ sl = es[e] & 255; dl = ed[e] & 255; }
    else { sl = dl = e - EPG; }
    int r = dl - lo;
    if ((unsigned)r < 64u){
      int p = atomicAdd(&cnt_s[r], 1);
      if (p < CAPQ) dst[p] = (unsigned char)sl;
    }
  }
}

// ---------------- GAT layer 1: edge-split scores ----------------
// grid 512: (gs=bid>>2, quarter=bid&3 -> 64 dsts), 512 thr, 8 thr/dst.
__global__ __launch_bounds__(512, 4) void gat1(
    const float* __restrict__ x1, const float* __restrict__ x2,
    const int* __restrict__ meta, const unsigned char* __restrict__ srcs,
    const float* __restrict__ Wl, const float* __restrict__ Wr,
    const float* __restrict__ bl, const float* __restrict__ br,
    const float* __restrict__ att, const float* __restrict__ bias,
    f16* __restrict__ hmid)
{
  __shared__ __align__(16) f16 xl_s[256 * 72];   // rows padded to 144B
  __shared__ float sc_s[CAPQ];
  __shared__ unsigned int src_su[SRCPAD / 4];
  __shared__ int start_s[64], deg_s[64];
  unsigned char* src_s = (unsigned char*)src_su;

  const int bid = blockIdx.x;
  const int gs = bid >> 2, lo = (bid & 3) * 64;
  const int side = gs >> 6, g = gs & 63;
  const float* x = side ? x2 : x1;
  const int t = threadIdx.x;

  // ---- load CSR meta + copy src list to LDS
  if (t < 64){
    start_s[t] = meta[bid * 128 + t];
    deg_s[t] = meta[bid * 128 + 64 + t];
  }
  int ttl = meta[bid * 128 + 63] + meta[bid * 128 + 64 + 63];
  if (ttl > CAPQ) ttl = CAPQ;
  {
    const unsigned int* gsrc = (const unsigned int*)(srcs + (size_t)bid * SRCPAD);
    int nw = (ttl + 3) >> 2;
    for (int i = t; i < nw; i += 512) src_su[i] = gsrc[i];
  }

  // ---- xl = x@Wl + bl: thread t -> node t>>1, dim-half t&1 (32 dims), f16 LDS
  {
    const int node = t >> 1, dh = t & 1;
    float xv[IND];
    const float* xr_ = x + (g * 256 + node) * IND;
#pragma unroll
    for (int k = 0; k < IND; k++) xv[k] = xr_[k];
#pragma unroll
    for (int ch = 0; ch < 4; ch++){
      f16x8 o;
#pragma unroll
      for (int j = 0; j < 8; j++){
        int dd = dh * 32 + ch * 8 + j;
        float a = bl[dd];
#pragma unroll
        for (int k = 0; k < IND; k++) a = fmaf(xv[k], Wl[k * HIDD + dd], a);
        o[j] = (f16)a;
      }
      *(f16x8*)&xl_s[node * 72 + dh * 32 + ch * 8] = o;
    }
  }

  // ---- 8 threads/dst: compute my 8 xr dims, then assemble all 64 via shfl
  const int pairi = t >> 3, sub = t & 7, ln = lo + pairi;
  f16x2 m[4], am[4];
  {
    float xv[IND];
    const float* xq = x + (g * 256 + ln) * IND;
#pragma unroll
    for (int k = 0; k < IND; k++) xv[k] = xq[k];
#pragma unroll
    for (int c = 0; c < 4; c++){
#pragma unroll
      for (int u = 0; u < 2; u++){
        int dd = sub * 8 + 2 * c + u;
        float a = br[dd];
#pragma unroll
        for (int k = 0; k < IND; k++) a = fmaf(xv[k], Wr[k * HIDD + dd], a);
        m[c][u] = (f16)a;
        am[c][u] = (f16)att[dd];
      }
    }
  }
  f16x2 xrh[32], atth[32];
  {
    const int base = (t & 63) & ~7;
#pragma unroll
    for (int ss = 0; ss < 8; ss++){
#pragma unroll
      for (int c = 0; c < 4; c++){
        xrh[ss * 4 + c] = shfl_h2(m[c], base + ss);
        atth[ss * 4 + c] = shfl_h2(am[c], base + ss);
      }
    }
  }
  __syncthreads();

  // ---- scores: edge-split (thread handles every-8th edge, full 64 dims)
  const int s0 = start_s[pairi];
  int sE = s0 + deg_s[pairi];
  if (sE > CAPQ) sE = CAPQ;
  float lmax = -3.0e38f;
  for (int idx = s0 + sub; idx < sE; idx += 8){
    int sl = src_s[idx];
    const f16x8* rp = (const f16x8*)&xl_s[(unsigned)sl * 72];
    float accs[4] = {0.f, 0.f, 0.f, 0.f};
#pragma unroll
    for (int blk = 0; blk < 8; blk++){
      f16x8 rv = rp[blk];
#pragma unroll
      for (int u = 0; u < 4; u++){
        f16x2 v = {rv[2 * u], rv[2 * u + 1]};
        v = v + xrh[blk * 4 + u];
        accs[u] = __builtin_amdgcn_fdot2(lrelu2(v), atth[blk * 4 + u], accs[u], false);
      }
    }
    float sc = (accs[0] + accs[1]) + (accs[2] + accs[3]);
    sc_s[idx] = sc;
    lmax = fmaxf(lmax, sc);
  }
  lmax = fmaxf(lmax, __shfl_xor(lmax, 1, 64));
  lmax = fmaxf(lmax, __shfl_xor(lmax, 2, 64));
  lmax = fmaxf(lmax, __shfl_xor(lmax, 4, 64));
  const float smax = lmax;
  // ---- softmax weights
  float ssum = 0.f;
  for (int idx = s0 + sub; idx < sE; idx += 8){
    float w = __expf(sc_s[idx] - smax);
    ssum += w;
    sc_s[idx] = w;
  }
  ssum += __shfl_xor(ssum, 1, 64);
  ssum += __shfl_xor(ssum, 2, 64);
  ssum += __shfl_xor(ssum, 4, 64);
  float inv = 1.f / ssum;
  // ---- aggregate alpha * xl[src], dim-split 8 ways
  float acc[8];
#pragma unroll
  for (int c = 0; c < 8; c++) acc[c] = 0.f;
  {
    int sl = (s0 < sE) ? src_s[s0] : 0;
    f16x8 row = *(const f16x8*)&xl_s[(unsigned)sl * 72 + sub * 8];
    for (int idx = s0; idx < sE; idx++){
      int sln = (idx + 1 < sE) ? src_s[idx + 1] : 0;
      f16x8 rown = *(const f16x8*)&xl_s[(unsigned)sln * 72 + sub * 8];
      float w = sc_s[idx];
#pragma unroll
      for (int c = 0; c < 8; c++) acc[c] = fmaf(w, (float)row[c], acc[c]);
      row = rown;
    }
  }
  f16x8 o;
#pragma unroll
  for (int c = 0; c < 8; c++)
    o[c] = (f16)fmaxf(acc[c] * inv + bias[sub * 8 + c], 0.f);
  *(f16x8*)(hmid + (size_t)(gs * 256 + ln) * 64 + sub * 8) = o;
}

// ---------------- lin2: [32768 x 64] @ [64 x 64] (Wl2|Wr2) via MFMA --------
__global__ __launch_bounds__(256) void lin2(
    const f16* __restrict__ hmid,
    const float* __restrict__ Wl, const float* __restrict__ Wr,
    const float* __restrict__ bl, const float* __restrict__ br,
    f16* __restrict__ xl2g, f16* __restrict__ xr2g)
{
  const int w = threadIdx.x >> 6, lane = threadIdx.x & 63;
  const int m = lane & 15, quad = lane >> 4;
  const int row0 = blockIdx.x * 64 + w * 16;

  const f16* arow = hmid + (size_t)(row0 + m) * 64;
  f16x8 a0 = *(const f16x8*)(arow + quad * 8);
  f16x8 a1 = *(const f16x8*)(arow + 32 + quad * 8);

#pragma unroll
  for (int c = 0; c < 4; c++){
    const int n = c * 16 + m;
    const float* W = (n < 32) ? Wl : Wr;
    const int nn = (n < 32) ? n : n - 32;
    f16x8 b0, b1;
#pragma unroll
    for (int j = 0; j < 8; j++){
      b0[j] = (f16)W[(quad * 8 + j) * 32 + nn];
      b1[j] = (f16)W[(32 + quad * 8 + j) * 32 + nn];
    }
    f32x4 acc = {0.f, 0.f, 0.f, 0.f};
    acc = __builtin_amdgcn_mfma_f32_16x16x32_f16(a0, b0, acc, 0, 0, 0);
    acc = __builtin_amdgcn_mfma_f32_16x16x32_f16(a1, b1, acc, 0, 0, 0);
    const float bv = (n < 32) ? bl[nn] : br[nn];
    f16* dst = (n < 32) ? xl2g : xr2g;
#pragma unroll
    for (int r = 0; r < 4; r++){
      int node = row0 + quad * 4 + r;
      dst[(size_t)node * 32 + nn] = (f16)(acc[r] + bv);
    }
  }
}

// ---------------- GAT layer 2: edge-split scores ----------------
__global__ __launch_bounds__(512, 4) void gat2(
    const int* __restrict__ meta, const unsigned char* __restrict__ srcs,
    const f16* __restrict__ xl2g, const f16* __restrict__ xr2g,
    const float* __restrict__ att, const float* __restrict__ bias,
    f16* __restrict__ hout)
{
  __shared__ __align__(16) f16 xl_s[256 * 40];   // rows padded to 80B
  __shared__ float sc_s[CAPQ];
  __shared__ unsigned int src_su[SRCPAD / 4];
  __shared__ int start_s[64], deg_s[64];
  unsigned char* src_s = (unsigned char*)src_su;

  const int bid = blockIdx.x;
  const int gs = bid >> 2, lo = (bid & 3) * 64;
  const int t = threadIdx.x;

  if (t < 64){
    start_s[t] = meta[bid * 128 + t];
    deg_s[t] = meta[bid * 128 + 64 + t];
  }
  int ttl = meta[bid * 128 + 63] + meta[bid * 128 + 64 + 63];
  if (ttl > CAPQ) ttl = CAPQ;
  {
    const unsigned int* gsrc = (const unsigned int*)(srcs + (size_t)bid * SRCPAD);
    int nw = (ttl + 3) >> 2;
    for (int i = t; i < nw; i += 512) src_su[i] = gsrc[i];
  }

  // ---- stage xl2 rows into padded LDS: 16 f16 per thread (two f16x8)
  {
    const int node = t >> 1, dh = t & 1;
    const f16* src = xl2g + (size_t)(gs * 256 + node) * 32 + dh * 16;
    f16x8 v0 = *(const f16x8*)(src);
    f16x8 v1 = *(const f16x8*)(src + 8);
    *(f16x8*)&xl_s[node * 40 + dh * 16] = v0;
    *(f16x8*)&xl_s[node * 40 + dh * 16 + 8] = v1;
  }

  // ---- 8 threads/dst: full 32-dim xr + att in regs (broadcast loads)
  const int pairi = t >> 3, sub = t & 7, ln = lo + pairi;
  f16x2 xrh[16], atth[16];
  {
    const f16x8* xrp = (const f16x8*)(xr2g + (size_t)(gs * 256 + ln) * 32);
#pragma unroll
    for (int q = 0; q < 4; q++){
      f16x8 v = xrp[q];
#pragma unroll
      for (int u = 0; u < 4; u++){
        xrh[q * 4 + u][0] = v[2 * u];
        xrh[q * 4 + u][1] = v[2 * u + 1];
      }
    }
#pragma unroll
    for (int i = 0; i < 16; i++){
      atth[i][0] = (f16)att[2 * i];
      atth[i][1] = (f16)att[2 * i + 1];
    }
  }
  __syncthreads();

  // ---- scores: edge-split
  const int s0 = start_s[pairi];
  int sE = s0 + deg_s[pairi];
  if (sE > CAPQ) sE = CAPQ;
  float lmax = -3.0e38f;
  for (int idx = s0 + sub; idx < sE; idx += 8){
    int sl = src_s[idx];
    const f16x8* rp = (const f16x8*)&xl_s[(unsigned)sl * 40];
    float accs[4] = {0.f, 0.f, 0.f, 0.f};
#pragma unroll
    for (int blk = 0; blk < 4; blk++){
      f16x8 rv = rp[blk];
#pragma unroll
      for (int u = 0; u < 4; u++){
        f16x2 v = {rv[2 * u], rv[2 * u + 1]};
        v = v + xrh[blk * 4 + u];
        accs[u] = __builtin_amdgcn_fdot2(lrelu2(v), atth[blk * 4 + u], accs[u], false);
      }
    }
    float sc = (accs[0] + accs[1]) + (accs[2] + accs[3]);
    sc_s[idx] = sc;
    lmax = fmaxf(lmax, sc);
  }
  lmax = fmaxf(lmax, __shfl_xor(lmax, 1, 64));
  lmax = fmaxf(lmax, __shfl_xor(lmax, 2, 64));
  lmax = fmaxf(lmax, __shfl_xor(lmax, 4, 64));
  const float smax = lmax;
  float ssum = 0.f;
  for (int idx = s0 + sub; idx < sE; idx += 8){
    float w = __expf(sc_s[idx] - smax);
    ssum += w;
    sc_s[idx] = w;
  }
  ssum += __shfl_xor(ssum, 1, 64);
  ssum += __shfl_xor(ssum, 2, 64);
  ssum += __shfl_xor(ssum, 4, 64);
  float inv = 1.f / ssum;

  float acc[4];
#pragma unroll
  for (int c = 0; c < 4; c++) acc[c] = 0.f;
  {
    int sl = (s0 < sE) ? src_s[s0] : 0;
    f16x4 row = *(const f16x4*)&xl_s[(unsigned)sl * 40 + sub * 4];
    for (int idx = s0; idx < sE; idx++){
      int sln = (idx + 1 < sE) ? src_s[idx + 1] : 0;
      f16x4 rown = *(const f16x4*)&xl_s[(unsigned)sln * 40 + sub * 4];
      float w = sc_s[idx];
#pragma unroll
      for (int c = 0; c < 4; c++) acc[c] = fmaf(w, (float)row[c], acc[c]);
      row = rown;
    }
  }
  f16x4 o;
#pragma unroll
  for (int c = 0; c < 4; c++)
    o[c] = (f16)(acc[c] * inv + bias[sub * 4 + c]);
  *(f16x4*)(hout + (size_t)(gs * 256 + ln) * 32 + sub * 4) = o;
}

// ---------------- sim (MFMA) + InstanceNorm + histogram Sinkhorn -----------
// grid 64, 1024 threads (16 waves). S_p sums computed from an 8192-bin
// histogram of z; exact z kept (as e^-z) in regs for the output pass.
__global__ __launch_bounds__(1024) void simtopk(
    const f16* __restrict__ H,
    const float* __restrict__ gamma, const float* __restrict__ beta,
    float* __restrict__ out)
{
  __shared__ float rb[16];
  __shared__ unsigned int hist[8192];
  const int b = blockIdx.x, t = threadIdx.x;
  const int w = t >> 6, lane = t & 63;
  const int m = lane & 15, quad = lane >> 4;

  const f16* h1 = H + (size_t)b * 256 * 32;
  const f16* h2 = H + (size_t)(64 + b) * 256 * 32;

  f16x8 av = *(const f16x8*)(h1 + (size_t)(w * 16 + m) * 32 + quad * 8);
  f32x4 c[16];
#pragma unroll
  for (int j = 0; j < 16; j++){
    f16x8 bv = *(const f16x8*)(h2 + (size_t)(j * 16 + m) * 32 + quad * 8);
    f32x4 z = {0.f, 0.f, 0.f, 0.f};
    c[j] = __builtin_amdgcn_mfma_f32_16x16x32_f16(av, bv, z, 0, 0, 0);
  }

  float sm = 0.f, s2 = 0.f, mn = 3.0e38f, mx = -3.0e38f;
#pragma unroll
  for (int j = 0; j < 16; j++)
#pragma unroll
    for (int r = 0; r < 4; r++){
      float s = c[j][r];
      sm += s; s2 = fmaf(s, s, s2);
      mn = fminf(mn, s); mx = fmaxf(mx, s);
    }
  sm = bsum16(sm, rb);
  s2 = bsum16(s2, rb);
  mn = bmin16(mn, rb);
  mx = bmax16(mx, rb);

  const float mu = sm * (1.f / 65536.f);
  const float var = s2 * (1.f / 65536.f) - mu * mu;
  const float a = gamma[0] * rsqrtf(var + 1e-5f);
  const float cc = beta[0] - a * mu;
  float mnn = a * mn + cc, mxn = a * mx + cc;
  if (a < 0.f){ float tmp = mnn; mnn = mxn; mxn = tmp; }
  const float al = 2.f * a;
  const float be = 2.f * cc - mnn - mxn;
  const float R = fmaxf(mxn - mnn, 1e-12f);       // z in [-R, R]
  const float binscale = 4096.f / R;

  // ---- zero + build histogram; cache e^-z in the acc regs
  for (int i = t; i < 8192; i += 1024) hist[i] = 0u;
  __syncthreads();
#pragma unroll
  for (int j = 0; j < 16; j++)
#pragma unroll
    for (int r = 0; r < 4; r++){
      float z = fmaf(al, c[j][r], be);
      int bi = (int)fmaf(z, binscale, 4096.f);
      bi = min(max(bi, 0), 8191);
      atomicAdd(&hist[bi], 1u);
      c[j][r] = __expf(-z);
    }
  __syncthreads();

  // ---- 5 S_p reductions over bins (8 bins/thread)
  const float wbin = R * (1.f / 4096.f);
  float ebs[8];
#pragma unroll
  for (int j = 0; j < 8; j++){
    float zc = fmaf((float)(t * 8 + j) + 0.5f, wbin, -R);
    ebs[j] = __expf(-zc);
  }
  float cnts[8];
#pragma unroll
  for (int j = 0; j < 8; j++) cnts[j] = (float)hist[t * 8 + j];

  float D = 0.f, S = 256.f, eD = 1.f;
  for (int p = 0; p < 5; p++){
    float loc = 0.f;
#pragma unroll
    for (int j = 0; j < 8; j++)
      loc += cnts[j] / (1.f + ebs[j] * eD);
    S = bsum16(loc, rb);
    if (p < 4){
      D += -5.5412635f /* log(256/65280) */ + __logf(65536.f - S) - __logf(S);
      eD = __expf(-D);
    }
  }

  const float scale = 256.f / S;
  float* ob = out + (size_t)b * 65536;
#pragma unroll
  for (int j = 0; j < 16; j++){
#pragma unroll
    for (int r = 0; r < 4; r++){
      float v = scale / (1.f + c[j][r] * eD);
      int row = w * 16 + quad * 4 + r;
      int col = j * 16 + m;
      ob[row * 256 + col] = fminf(v, 1.f);
    }
  }
}

extern "C" void kernel_launch(void* const* d_in, const int* in_sizes, int n_in,
                              void* d_out, int out_size, void* d_ws, size_t ws_size,
                              hipStream_t stream)
{
  const float* x1   = (const float*)d_in[0];
  const float* x2   = (const float*)d_in[1];
  const int*   e1   = (const int*)d_in[2];
  const int*   e2   = (const int*)d_in[3];
  const float* Wl1  = (const float*)d_in[4];
  const float* Wr1  = (const float*)d_in[5];
  const float* bl1  = (const float*)d_in[6];
  const float* br1  = (const float*)d_in[7];
  const float* att1 = (const float*)d_in[8];
  const float* bias1= (const float*)d_in[9];
  const float* Wl2  = (const float*)d_in[10];
  const float* Wr2  = (const float*)d_in[11];
  const float* bl2  = (const float*)d_in[12];
  const float* br2  = (const float*)d_in[13];
  const float* att2 = (const float*)d_in[14];
  const float* bias2= (const float*)d_in[15];
  const float* gamma= (const float*)d_in[16];
  const float* beta = (const float*)d_in[17];

  // ws: hmid [0,4M) (dead after lin2; hfin aliases [2,4M)); xl2g [4,6M);
  // xr2g [6,8M); csr meta [8M,+256K); csr srcs [+256K, +1.31M) => ~9.6 MB.
  char* ws = (char*)d_ws;
  f16* hmid = (f16*)ws;
  f16* hfin = (f16*)(ws + (size_t)2 * 1024 * 1024);
  f16* xl2g = (f16*)(ws + (size_t)4 * 1024 * 1024);
  f16* xr2g = (f16*)(ws + (size_t)6 * 1024 * 1024);
  int* meta = (int*)(ws + (size_t)8 * 1024 * 1024);
  unsigned char* srcs = (unsigned char*)(ws + (size_t)8 * 1024 * 1024 + 512 * 128 * 4);
  float* out = (float*)d_out;

  csrk<<<512, 256, 0, stream>>>(e1, e2, meta, srcs);
  gat1<<<512, 512, 0, stream>>>(x1, x2, meta, srcs, Wl1, Wr1, bl1, br1, att1, bias1, hmid);
  lin2<<<512, 256, 0, stream>>>(hmid, Wl2, Wr2, bl2, br2, xl2g, xr2g);
  gat2<<<512, 512, 0, stream>>>(meta, srcs, xl2g, xr2g, att2, bias2, hfin);
  simtopk<<<64, 1024, 0, stream>>>(hfin, gamma, beta, out);
}

// Round 6
// 188.054 us; speedup vs baseline: 2.0949x; 1.1129x over previous
//
#include <hip/hip_runtime.h>

#define NB 64
#define NN 256
#define IND 7
#define HIDD 64
#define OUTD 32
#define EPG 8192
#define ETOT 524288
#define CAPQ 2600     // CSR capacity per 64-dst quarter (mean 2112, ~12 sigma)
#define SRCPAD 2624   // CAPQ rounded to 16

typedef _Float16 f16;
typedef f16 f16x2 __attribute__((ext_vector_type(2)));
typedef f16 f16x4 __attribute__((ext_vector_type(4)));
typedef f16 f16x8 __attribute__((ext_vector_type(8)));
typedef float f32x4 __attribute__((ext_vector_type(4)));

// ---------------- block reductions for 16-wave blocks ----------------
__device__ __forceinline__ float bsum16(float v, float* rb){
#pragma unroll
  for (int o = 32; o > 0; o >>= 1) v += __shfl_xor(v, o, 64);
  __syncthreads();
  if ((threadIdx.x & 63) == 0) rb[threadIdx.x >> 6] = v;
  __syncthreads();
  float s = 0.f;
#pragma unroll
  for (int i = 0; i < 16; i++) s += rb[i];
  return s;
}
__device__ __forceinline__ float bmin16(float v, float* rb){
#pragma unroll
  for (int o = 32; o > 0; o >>= 1) v = fminf(v, __shfl_xor(v, o, 64));
  __syncthreads();
  if ((threadIdx.x & 63) == 0) rb[threadIdx.x >> 6] = v;
  __syncthreads();
  float s = rb[0];
#pragma unroll
  for (int i = 1; i < 16; i++) s = fminf(s, rb[i]);
  return s;
}
__device__ __forceinline__ float bmax16(float v, float* rb){
#pragma unroll
  for (int o = 32; o > 0; o >>= 1) v = fmaxf(v, __shfl_xor(v, o, 64));
  __syncthreads();
  if ((threadIdx.x & 63) == 0) rb[threadIdx.x >> 6] = v;
  __syncthreads();
  float s = rb[0];
#pragma unroll
  for (int i = 1; i < 16; i++) s = fmaxf(s, rb[i]);
  return s;
}

__device__ __forceinline__ f16x2 lrelu2(f16x2 s){
  const f16x2 k = {(f16)0.2f, (f16)0.2f};
  return __builtin_elementwise_max(s, s * k);
}
__device__ __forceinline__ f16x2 shfl_h2(f16x2 v, int lane){
  int i = __builtin_bit_cast(int, v);
  i = __shfl(i, lane, 64);
  return __builtin_bit_cast(f16x2, i);
}

// ---------------- GAT layer 1 + CSR build (fused) ----------------
// grid 512: (gs=bid>>2, quarter=bid&3 -> 64 dsts), 512 thr, 8 thr/dst.
// Builds CSR in LDS, uses it, and writes it to global for gat2's reuse.
__global__ __launch_bounds__(512, 4) void gat1(
    const float* __restrict__ x1, const float* __restrict__ x2,
    const int* __restrict__ e1, const int* __restrict__ e2,
    const float* __restrict__ Wl, const float* __restrict__ Wr,
    const float* __restrict__ bl, const float* __restrict__ br,
    const float* __restrict__ att, const float* __restrict__ bias,
    f16* __restrict__ hmid,
    int* __restrict__ meta, unsigned char* __restrict__ srcs)
{
  __shared__ __align__(16) f16 xl_s[256 * 72];   // rows padded to 144B
  __shared__ float sc_s[CAPQ];
  __shared__ unsigned int src_su[SRCPAD / 4];
  __shared__ int deg_s[64], start_s[64], cnt_s[64];
  unsigned char* src_s = (unsigned char*)src_su;

  const int bid = blockIdx.x;
  const int gs = bid >> 2, lo = (bid & 3) * 64;
  const int side = gs >> 6, g = gs & 63;
  const float* x = side ? x2 : x1;
  const int* eb = side ? e2 : e1;
  const int* es = eb + g * EPG;
  const int* ed = eb + ETOT + g * EPG;
  const int t = threadIdx.x;

  if (t < 64) deg_s[t] = 0;

  // ---- xl = x@Wl + bl: thread t -> node t>>1, dim-half t&1 (32 dims), f16 LDS
  {
    const int node = t >> 1, dh = t & 1;
    float xv[IND];
    const float* xr_ = x + (g * 256 + node) * IND;
#pragma unroll
    for (int k = 0; k < IND; k++) xv[k] = xr_[k];
#pragma unroll
    for (int ch = 0; ch < 4; ch++){
      f16x8 o;
#pragma unroll
      for (int j = 0; j < 8; j++){
        int dd = dh * 32 + ch * 8 + j;
        float a = bl[dd];
#pragma unroll
        for (int k = 0; k < IND; k++) a = fmaf(xv[k], Wl[k * HIDD + dd], a);
        o[j] = (f16)a;
      }
      *(f16x8*)&xl_s[node * 72 + dh * 32 + ch * 8] = o;
    }
  }

  // ---- 8 threads/dst: compute my 8 xr dims, then assemble all 64 via shfl
  const int pairi = t >> 3, sub = t & 7, ln = lo + pairi;
  f16x2 m[4], am[4];
  {
    float xv[IND];
    const float* xq = x + (g * 256 + ln) * IND;
#pragma unroll
    for (int k = 0; k < IND; k++) xv[k] = xq[k];
#pragma unroll
    for (int c = 0; c < 4; c++){
#pragma unroll
      for (int u = 0; u < 2; u++){
        int dd = sub * 8 + 2 * c + u;
        float a = br[dd];
#pragma unroll
        for (int k = 0; k < IND; k++) a = fmaf(xv[k], Wr[k * HIDD + dd], a);
        m[c][u] = (f16)a;
        am[c][u] = (f16)att[dd];
      }
    }
  }
  f16x2 xrh[32], atth[32];
  {
    const int base = (t & 63) & ~7;
#pragma unroll
    for (int ss = 0; ss < 8; ss++){
#pragma unroll
      for (int c = 0; c < 4; c++){
        xrh[ss * 4 + c] = shfl_h2(m[c], base + ss);
        atth[ss * 4 + c] = shfl_h2(am[c], base + ss);
      }
    }
  }
  __syncthreads();   // deg zero + xl_s visible

  // ---- CSR count pass
  for (int e = t; e < EPG + 256; e += 512){
    int dl = (e < EPG) ? (ed[e] & 255) : (e - EPG);
    int r = dl - lo;
    if ((unsigned)r < 64u) atomicAdd(&deg_s[r], 1);
  }
  __syncthreads();
  // ---- scan + publish meta
  if (t < 64){
    int v = deg_s[t], s = v;
#pragma unroll
    for (int off = 1; off < 64; off <<= 1){
      int u = __shfl_up(s, off, 64);
      if (t >= off) s += u;
    }
    start_s[t] = s - v;
    cnt_s[t] = s - v;
    meta[bid * 128 + t] = s - v;
    meta[bid * 128 + 64 + t] = v;
  }
  __syncthreads();
  // ---- fill pass
  for (int e = t; e < EPG + 256; e += 512){
    int sl, dl;
    if (e < EPG){ sl = es[e] & 255; dl = ed[e] & 255; }
    else { sl = dl = e - EPG; }
    int r = dl - lo;
    if ((unsigned)r < 64u){
      int p = atomicAdd(&cnt_s[r], 1);
      if (p < CAPQ) src_s[p] = (unsigned char)sl;
    }
  }
  __syncthreads();
  // ---- dump CSR srcs to global for gat2 (coalesced u32)
  {
    int ttl = start_s[63] + deg_s[63];
    if (ttl > CAPQ) ttl = CAPQ;
    unsigned int* gsrc = (unsigned int*)(srcs + (size_t)bid * SRCPAD);
    int nw = (ttl + 3) >> 2;
    for (int i = t; i < nw; i += 512) gsrc[i] = src_su[i];
  }

  // ---- scores: edge-split (thread handles every-8th edge, full 64 dims)
  const int s0 = start_s[pairi];
  int sE = s0 + deg_s[pairi];
  if (sE > CAPQ) sE = CAPQ;
  float lmax = -3.0e38f;
  for (int idx = s0 + sub; idx < sE; idx += 8){
    int sl = src_s[idx];
    const f16x8* rp = (const f16x8*)&xl_s[(unsigned)sl * 72];
    float accs[4] = {0.f, 0.f, 0.f, 0.f};
#pragma unroll
    for (int blk = 0; blk < 8; blk++){
      f16x8 rv = rp[blk];
#pragma unroll
      for (int u = 0; u < 4; u++){
        f16x2 v = {rv[2 * u], rv[2 * u + 1]};
        v = v + xrh[blk * 4 + u];
        accs[u] = __builtin_amdgcn_fdot2(lrelu2(v), atth[blk * 4 + u], accs[u], false);
      }
    }
    float sc = (accs[0] + accs[1]) + (accs[2] + accs[3]);
    sc_s[idx] = sc;
    lmax = fmaxf(lmax, sc);
  }
  lmax = fmaxf(lmax, __shfl_xor(lmax, 1, 64));
  lmax = fmaxf(lmax, __shfl_xor(lmax, 2, 64));
  lmax = fmaxf(lmax, __shfl_xor(lmax, 4, 64));
  const float smax = lmax;
  // ---- softmax weights
  float ssum = 0.f;
  for (int idx = s0 + sub; idx < sE; idx += 8){
    float w = __expf(sc_s[idx] - smax);
    ssum += w;
    sc_s[idx] = w;
  }
  ssum += __shfl_xor(ssum, 1, 64);
  ssum += __shfl_xor(ssum, 2, 64);
  ssum += __shfl_xor(ssum, 4, 64);
  float inv = 1.f / ssum;
  // ---- aggregate alpha * xl[src], dim-split 8 ways
  float acc[8];
#pragma unroll
  for (int c = 0; c < 8; c++) acc[c] = 0.f;
  {
    int sl = (s0 < sE) ? src_s[s0] : 0;
    f16x8 row = *(const f16x8*)&xl_s[(unsigned)sl * 72 + sub * 8];
    for (int idx = s0; idx < sE; idx++){
      int sln = (idx + 1 < sE) ? src_s[idx + 1] : 0;
      f16x8 rown = *(const f16x8*)&xl_s[(unsigned)sln * 72 + sub * 8];
      float w = sc_s[idx];
#pragma unroll
      for (int c = 0; c < 8; c++) acc[c] = fmaf(w, (float)row[c], acc[c]);
      row = rown;
    }
  }
  f16x8 o;
#pragma unroll
  for (int c = 0; c < 8; c++)
    o[c] = (f16)fmaxf(acc[c] * inv + bias[sub * 8 + c], 0.f);
  *(f16x8*)(hmid + (size_t)(gs * 256 + ln) * 64 + sub * 8) = o;
}

// ---------------- GAT layer 2 + lin2 (fused) ----------------
// grid 512, 512 thr. In-block MFMA computes xl2 (all 256 nodes) and xr2
// (own 64 dsts) from hmid straight into LDS; then edge-split GAT as before.
__global__ __launch_bounds__(512, 4) void gat2(
    const int* __restrict__ meta, const unsigned char* __restrict__ srcs,
    const f16* __restrict__ hmid,
    const float* __restrict__ Wl, const float* __restrict__ Wr,
    const float* __restrict__ bl, const float* __restrict__ br,
    const float* __restrict__ att, const float* __restrict__ bias,
    f16* __restrict__ hout)
{
  __shared__ __align__(16) f16 xl_s[256 * 40];   // rows padded to 80B
  __shared__ __align__(16) f16 xr_s[64 * 40];
  __shared__ float sc_s[CAPQ];
  __shared__ unsigned int src_su[SRCPAD / 4];
  __shared__ int start_s[64], deg_s[64];
  unsigned char* src_s = (unsigned char*)src_su;

  const int bid = blockIdx.x;
  const int gs = bid >> 2, lo = (bid & 3) * 64;
  const int t = threadIdx.x;

  // ---- CSR load (global -> LDS)
  if (t < 64){
    start_s[t] = meta[bid * 128 + t];
    deg_s[t] = meta[bid * 128 + 64 + t];
  }
  {
    int ttl = meta[bid * 128 + 63] + meta[bid * 128 + 64 + 63];
    if (ttl > CAPQ) ttl = CAPQ;
    const unsigned int* gsrc = (const unsigned int*)(srcs + (size_t)bid * SRCPAD);
    int nw = (ttl + 3) >> 2;
    for (int i = t; i < nw; i += 512) src_su[i] = gsrc[i];
  }

  // ---- in-block lin2 via MFMA: wave w -> node tiles {2w, 2w+1} for xl2;
  //      waves 0..3 also compute xr2 for own dst tile.
  {
    const int w = t >> 6, lane = t & 63;
    const int m = lane & 15, quad = lane >> 4;
    // A-frags for the two xl2 tiles
    f16x8 a[2][2];
#pragma unroll
    for (int ti = 0; ti < 2; ti++){
      const f16* arow = hmid + (size_t)(gs * 256 + (2 * w + ti) * 16 + m) * 64;
      a[ti][0] = *(const f16x8*)(arow + quad * 8);
      a[ti][1] = *(const f16x8*)(arow + 32 + quad * 8);
    }
#pragma unroll
    for (int H = 0; H < 2; H++){
      const int n = H * 16 + m;
      f16x8 b0, b1;
#pragma unroll
      for (int j = 0; j < 8; j++){
        b0[j] = (f16)Wl[(quad * 8 + j) * 32 + n];
        b1[j] = (f16)Wl[(32 + quad * 8 + j) * 32 + n];
      }
      const float bv = bl[n];
#pragma unroll
      for (int ti = 0; ti < 2; ti++){
        f32x4 acc = {0.f, 0.f, 0.f, 0.f};
        acc = __builtin_amdgcn_mfma_f32_16x16x32_f16(a[ti][0], b0, acc, 0, 0, 0);
        acc = __builtin_amdgcn_mfma_f32_16x16x32_f16(a[ti][1], b1, acc, 0, 0, 0);
#pragma unroll
        for (int r = 0; r < 4; r++)
          xl_s[((2 * w + ti) * 16 + quad * 4 + r) * 40 + n] = (f16)(acc[r] + bv);
      }
    }
    if (w < 4){
      const f16* arow = hmid + (size_t)(gs * 256 + lo + w * 16 + m) * 64;
      f16x8 c0 = *(const f16x8*)(arow + quad * 8);
      f16x8 c1 = *(const f16x8*)(arow + 32 + quad * 8);
#pragma unroll
      for (int H = 0; H < 2; H++){
        const int n = H * 16 + m;
        f16x8 b0, b1;
#pragma unroll
        for (int j = 0; j < 8; j++){
          b0[j] = (f16)Wr[(quad * 8 + j) * 32 + n];
          b1[j] = (f16)Wr[(32 + quad * 8 + j) * 32 + n];
        }
        const float bv = br[n];
        f32x4 acc = {0.f, 0.f, 0.f, 0.f};
        acc = __builtin_amdgcn_mfma_f32_16x16x32_f16(c0, b0, acc, 0, 0, 0);
        acc = __builtin_amdgcn_mfma_f32_16x16x32_f16(c1, b1, acc, 0, 0, 0);
#pragma unroll
        for (int r = 0; r < 4; r++)
          xr_s[(w * 16 + quad * 4 + r) * 40 + n] = (f16)(acc[r] + bv);
      }
    }
  }
  __syncthreads();

  // ---- 8 threads/dst: full 32-dim xr + att in regs (LDS broadcast reads)
  const int pairi = t >> 3, sub = t & 7, ln = lo + pairi;
  f16x2 xrh[16], atth[16];
  {
    const f16x8* xrp = (const f16x8*)&xr_s[pairi * 40];
#pragma unroll
    for (int q = 0; q < 4; q++){
      f16x8 v = xrp[q];
#pragma unroll
      for (int u = 0; u < 4; u++){
        xrh[q * 4 + u][0] = v[2 * u];
        xrh[q * 4 + u][1] = v[2 * u + 1];
      }
    }
#pragma unroll
    for (int i = 0; i < 16; i++){
      atth[i][0] = (f16)att[2 * i];
      atth[i][1] = (f16)att[2 * i + 1];
    }
  }

  // ---- scores: edge-split
  const int s0 = start_s[pairi];
  int sE = s0 + deg_s[pairi];
  if (sE > CAPQ) sE = CAPQ;
  float lmax = -3.0e38f;
  for (int idx = s0 + sub; idx < sE; idx += 8){
    int sl = src_s[idx];
    const f16x8* rp = (const f16x8*)&xl_s[(unsigned)sl * 40];
    float accs[4] = {0.f, 0.f, 0.f, 0.f};
#pragma unroll
    for (int blk = 0; blk < 4; blk++){
      f16x8 rv = rp[blk];
#pragma unroll
      for (int u = 0; u < 4; u++){
        f16x2 v = {rv[2 * u], rv[2 * u + 1]};
        v = v + xrh[blk * 4 + u];
        accs[u] = __builtin_amdgcn_fdot2(lrelu2(v), atth[blk * 4 + u], accs[u], false);
      }
    }
    float sc = (accs[0] + accs[1]) + (accs[2] + accs[3]);
    sc_s[idx] = sc;
    lmax = fmaxf(lmax, sc);
  }
  lmax = fmaxf(lmax, __shfl_xor(lmax, 1, 64));
  lmax = fmaxf(lmax, __shfl_xor(lmax, 2, 64));
  lmax = fmaxf(lmax, __shfl_xor(lmax, 4, 64));
  const float smax = lmax;
  float ssum = 0.f;
  for (int idx = s0 + sub; idx < sE; idx += 8){
    float w = __expf(sc_s[idx] - smax);
    ssum += w;
    sc_s[idx] = w;
  }
  ssum += __shfl_xor(ssum, 1, 64);
  ssum += __shfl_xor(ssum, 2, 64);
  ssum += __shfl_xor(ssum, 4, 64);
  float inv = 1.f / ssum;

  float acc[4];
#pragma unroll
  for (int c = 0; c < 4; c++) acc[c] = 0.f;
  {
    int sl = (s0 < sE) ? src_s[s0] : 0;
    f16x4 row = *(const f16x4*)&xl_s[(unsigned)sl * 40 + sub * 4];
    for (int idx = s0; idx < sE; idx++){
      int sln = (idx + 1 < sE) ? src_s[idx + 1] : 0;
      f16x4 rown = *(const f16x4*)&xl_s[(unsigned)sln * 40 + sub * 4];
      float w = sc_s[idx];
#pragma unroll
      for (int c = 0; c < 4; c++) acc[c] = fmaf(w, (float)row[c], acc[c]);
      row = rown;
    }
  }
  f16x4 o;
#pragma unroll
  for (int c = 0; c < 4; c++)
    o[c] = (f16)(acc[c] * inv + bias[sub * 4 + c]);
  *(f16x4*)(hout + (size_t)(gs * 256 + ln) * 32 + sub * 4) = o;
}

// ---------------- sim (MFMA) + InstanceNorm + histogram Sinkhorn -----------
__global__ __launch_bounds__(1024) void simtopk(
    const f16* __restrict__ H,
    const float* __restrict__ gamma, const float* __restrict__ beta,
    float* __restrict__ out)
{
  __shared__ float rb[16];
  __shared__ unsigned int hist[8192];
  const int b = blockIdx.x, t = threadIdx.x;
  const int w = t >> 6, lane = t & 63;
  const int m = lane & 15, quad = lane >> 4;

  const f16* h1 = H + (size_t)b * 256 * 32;
  const f16* h2 = H + (size_t)(64 + b) * 256 * 32;

  f16x8 av = *(const f16x8*)(h1 + (size_t)(w * 16 + m) * 32 + quad * 8);
  f32x4 c[16];
#pragma unroll
  for (int j = 0; j < 16; j++){
    f16x8 bv = *(const f16x8*)(h2 + (size_t)(j * 16 + m) * 32 + quad * 8);
    f32x4 z = {0.f, 0.f, 0.f, 0.f};
    c[j] = __builtin_amdgcn_mfma_f32_16x16x32_f16(av, bv, z, 0, 0, 0);
  }

  float sm = 0.f, s2 = 0.f, mn = 3.0e38f, mx = -3.0e38f;
#pragma unroll
  for (int j = 0; j < 16; j++)
#pragma unroll
    for (int r = 0; r < 4; r++){
      float s = c[j][r];
      sm += s; s2 = fmaf(s, s, s2);
      mn = fminf(mn, s); mx = fmaxf(mx, s);
    }
  sm = bsum16(sm, rb);
  s2 = bsum16(s2, rb);
  mn = bmin16(mn, rb);
  mx = bmax16(mx, rb);

  const float mu = sm * (1.f / 65536.f);
  const float var = s2 * (1.f / 65536.f) - mu * mu;
  const float a = gamma[0] * rsqrtf(var + 1e-5f);
  const float cc = beta[0] - a * mu;
  float mnn = a * mn + cc, mxn = a * mx + cc;
  if (a < 0.f){ float tmp = mnn; mnn = mxn; mxn = tmp; }
  const float al = 2.f * a;
  const float be = 2.f * cc - mnn - mxn;
  const float R = fmaxf(mxn - mnn, 1e-12f);       // z in [-R, R]
  const float binscale = 4096.f / R;

  // ---- zero + build histogram; cache e^-z in the acc regs
  for (int i = t; i < 8192; i += 1024) hist[i] = 0u;
  __syncthreads();
#pragma unroll
  for (int j = 0; j < 16; j++)
#pragma unroll
    for (int r = 0; r < 4; r++){
      float z = fmaf(al, c[j][r], be);
      int bi = (int)fmaf(z, binscale, 4096.f);
      bi = min(max(bi, 0), 8191);
      atomicAdd(&hist[bi], 1u);
      c[j][r] = __expf(-z);
    }
  __syncthreads();

  // ---- 5 S_p reductions over bins (8 bins/thread)
  const float wbin = R * (1.f / 4096.f);
  float ebs[8];
#pragma unroll
  for (int j = 0; j < 8; j++){
    float zc = fmaf((float)(t * 8 + j) + 0.5f, wbin, -R);
    ebs[j] = __expf(-zc);
  }
  float cnts[8];
#pragma unroll
  for (int j = 0; j < 8; j++) cnts[j] = (float)hist[t * 8 + j];

  float D = 0.f, S = 256.f, eD = 1.f;
  for (int p = 0; p < 5; p++){
    float loc = 0.f;
#pragma unroll
    for (int j = 0; j < 8; j++)
      loc += cnts[j] / (1.f + ebs[j] * eD);
    S = bsum16(loc, rb);
    if (p < 4){
      D += -5.5412635f /* log(256/65280) */ + __logf(65536.f - S) - __logf(S);
      eD = __expf(-D);
    }
  }

  const float scale = 256.f / S;
  float* ob = out + (size_t)b * 65536;
#pragma unroll
  for (int j = 0; j < 16; j++){
#pragma unroll
    for (int r = 0; r < 4; r++){
      float v = scale / (1.f + c[j][r] * eD);
      int row = w * 16 + quad * 4 + r;
      int col = j * 16 + m;
      ob[row * 256 + col] = fminf(v, 1.f);
    }
  }
}

extern "C" void kernel_launch(void* const* d_in, const int* in_sizes, int n_in,
                              void* d_out, int out_size, void* d_ws, size_t ws_size,
                              hipStream_t stream)
{
  const float* x1   = (const float*)d_in[0];
  const float* x2   = (const float*)d_in[1];
  const int*   e1   = (const int*)d_in[2];
  const int*   e2   = (const int*)d_in[3];
  const float* Wl1  = (const float*)d_in[4];
  const float* Wr1  = (const float*)d_in[5];
  const float* bl1  = (const float*)d_in[6];
  const float* br1  = (const float*)d_in[7];
  const float* att1 = (const float*)d_in[8];
  const float* bias1= (const float*)d_in[9];
  const float* Wl2  = (const float*)d_in[10];
  const float* Wr2  = (const float*)d_in[11];
  const float* bl2  = (const float*)d_in[12];
  const float* br2  = (const float*)d_in[13];
  const float* att2 = (const float*)d_in[14];
  const float* bias2= (const float*)d_in[15];
  const float* gamma= (const float*)d_in[16];
  const float* beta = (const float*)d_in[17];

  // ws: hmid [0,4M); hfin [4M,6M); meta [6M,+256K); srcs [+256K,+1.6M)
  char* ws = (char*)d_ws;
  f16* hmid = (f16*)ws;
  f16* hfin = (f16*)(ws + (size_t)4 * 1024 * 1024);
  int* meta = (int*)(ws + (size_t)6 * 1024 * 1024);
  unsigned char* srcs = (unsigned char*)(ws + (size_t)6 * 1024 * 1024 + 512 * 128 * 4);
  float* out = (float*)d_out;

  gat1<<<512, 512, 0, stream>>>(x1, x2, e1, e2, Wl1, Wr1, bl1, br1, att1, bias1,
                                hmid, meta, srcs);
  gat2<<<512, 512, 0, stream>>>(meta, srcs, hmid, Wl2, Wr2, bl2, br2, att2, bias2, hfin);
  simtopk<<<64, 1024, 0, stream>>>(hfin, gamma, beta, out);
}